// Round 5
// baseline (332.895 us; speedup 1.0000x reference)
//
#include <hip/hip_runtime.h>
#include <hip/hip_bf16.h>

typedef unsigned short u16;
typedef unsigned int   u32;
typedef short v8s __attribute__((ext_vector_type(8)));
typedef float v4f __attribute__((ext_vector_type(4)));
typedef float v16f __attribute__((ext_vector_type(16)));
typedef int   v2i __attribute__((ext_vector_type(2)));

#define MFMA16(a,b,c) __builtin_amdgcn_mfma_f32_16x16x32_bf16(a,b,c,0,0,0)
#define MFMA32(a,b,c) __builtin_amdgcn_mfma_f32_32x32x16_bf16(a,b,c,0,0,0)

// Harness I/O dtype is FP32 (confirmed R11-R13 bisect). Internals bf16.
// Softmax scale C2 folded into Qp at proj; CB shift cancels in O/l.

__device__ __forceinline__ u16 f2b(float f){ u32 i; __builtin_memcpy(&i,&f,4); u32 r = (i + 0x7FFFu + ((i>>16)&1u))>>16; return (u16)r; }
__device__ __forceinline__ u32 pk2(float a, float b){
  __hip_bfloat162 h = __float22bfloat162_rn(make_float2(a,b));
  u32 r; __builtin_memcpy(&r,&h,4); return r;
}

// async global->LDS DMA, 16B per lane (bf16 sources only).
__device__ __forceinline__ void gl16(const void* g, void* l){
  __builtin_amdgcn_global_load_lds((const __attribute__((address_space(1))) u32*)g,
                                   (__attribute__((address_space(3))) u32*)l, 16, 0, 0);
}

// fp32 staging: 8 f32 -> 8 bf16 into LDS via packed v_cvt_pk_bf16_f32
__device__ __forceinline__ void stage8f(const float* g, u16* l){
  float4 a = *(const float4*)g, b = *(const float4*)(g+4);
  uint4 q;
  q.x = pk2(a.x, a.y); q.y = pk2(a.z, a.w);
  q.z = pk2(b.x, b.y); q.w = pk2(b.z, b.w);
  *(uint4*)l = q;
}

// ---------------------------------------------------------------------------
// Kernel 1: fused QKV projection (R15, unchanged). Inputs fp32, internals bf16.
// z=0: Qp[B,H,S,D] (PRE-SCALED by C2), z=1: Kp, z=2: Vt[B,H,D,S] transpose.
// ---------------------------------------------------------------------------
__global__ __launch_bounds__(256) void proj_qkv(
    const float* __restrict__ Qx, const float* __restrict__ Kx, const float* __restrict__ Vx,
    const float* __restrict__ WQw, const float* __restrict__ WQb,
    const float* __restrict__ WKw, const float* __restrict__ WKb,
    const float* __restrict__ WVw, const float* __restrict__ WVb,
    u16* __restrict__ Qp, u16* __restrict__ Kp, u16* __restrict__ Vt)
{
  __shared__ u16 smem[32768];          // As(16384) + Ws(16384); reused as Cs
  u16* As = smem;
  u16* Ws = smem + 16384;

  const int z = blockIdx.z;
  const float* X    = (z==0) ? Qx  : (z==1 ? Kx  : Vx);
  const float* W    = (z==0) ? WQw : (z==1 ? WKw : WVw);
  const float* bias = (z==0) ? WQb : (z==1 ? WKb : WVb);
  u16* out          = (z==0) ? Qp  : (z==1 ? Kp  : Vt);
  const float qs    = (z==0) ? 0.12751743076f : 1.0f;   // C2 fold into Q

  const int tid = threadIdx.x, wv = tid>>6, lane = tid&63;
  const int quad = lane>>4, l16 = lane&15;
  const int r4 = lane>>2, c4 = lane&3;
  const int m0 = blockIdx.x*128, n0 = blockIdx.y*128;

  for (int idx = wv; idx < 32; idx += 4) {
    int kt = idx >> 3, rg = idx & 7;
    int row = rg*16 + r4;
    stage8f(X + (size_t)(m0+row)*128 + kt*32 + c4*8, &As[kt*4096 + rg*512 + lane*8]);
    stage8f(W + (size_t)(n0+row)*128 + kt*32 + c4*8, &Ws[kt*4096 + rg*512 + lane*8]);
  }
  __syncthreads();

  const int wm = wv & 1, wn = wv >> 1;
  v4f acc[4][4];
#pragma unroll
  for (int i=0;i<4;i++)
#pragma unroll
    for (int j=0;j<4;j++) acc[i][j] = (v4f){0.f,0.f,0.f,0.f};

  if (z < 2) {
#pragma unroll
    for (int ks=0; ks<4; ++ks) {
      v8s af[4], bf[4];
#pragma unroll
      for (int mi=0; mi<4; ++mi) af[mi] = *(const v8s*)&As[ks*4096 + (wm*64+mi*16+l16)*32 + quad*8];
#pragma unroll
      for (int ni=0; ni<4; ++ni) bf[ni] = *(const v8s*)&Ws[ks*4096 + (wn*64+ni*16+l16)*32 + quad*8];
#pragma unroll
      for (int mi=0; mi<4; ++mi)
#pragma unroll
        for (int ni=0; ni<4; ++ni)
          acc[mi][ni] = MFMA16(bf[ni], af[mi], acc[mi][ni]);   // A=W, B=X
    }
#pragma unroll
    for (int ni=0; ni<4; ++ni) {
      int nb = n0 + wn*64 + ni*16 + quad*4;   // global n, 4 consecutive (r)
      float bv0 = bias[nb+0]*qs;
      float bv1 = bias[nb+1]*qs;
      float bv2 = bias[nb+2]*qs;
      float bv3 = bias[nb+3]*qs;
      int h = n0 >> 7, dh = nb & 127;
#pragma unroll
      for (int mi=0; mi<4; ++mi) {
        int m = m0 + wm*64 + mi*16 + l16;
        int b = m >> 11, s = m & 2047;
        uint2 pk;
        pk.x = pk2(fmaf(acc[mi][ni][0], qs, bv0), fmaf(acc[mi][ni][1], qs, bv1));
        pk.y = pk2(fmaf(acc[mi][ni][2], qs, bv2), fmaf(acc[mi][ni][3], qs, bv3));
        *(uint2*)&out[(size_t)(((b<<3) + h)*2048 + s)*128 + dh] = pk;
      }
    }
  } else {
#pragma unroll
    for (int ks=0; ks<4; ++ks) {
      v8s af[4], bf[4];
#pragma unroll
      for (int mi=0; mi<4; ++mi) af[mi] = *(const v8s*)&As[ks*4096 + (wm*64+mi*16+l16)*32 + quad*8];
#pragma unroll
      for (int ni=0; ni<4; ++ni) bf[ni] = *(const v8s*)&Ws[ks*4096 + (wn*64+ni*16+l16)*32 + quad*8];
#pragma unroll
      for (int mi=0; mi<4; ++mi)
#pragma unroll
        for (int ni=0; ni<4; ++ni)
          acc[mi][ni] = MFMA16(af[mi], bf[ni], acc[mi][ni]);
    }
    __syncthreads();               // all waves done reading As/Ws
    u16* Cs = smem;                // Cs[n][136]
#pragma unroll
    for (int ni=0; ni<4; ++ni) {
      int nl = wn*64 + ni*16 + l16;
      float bv = bias[n0 + nl];
#pragma unroll
      for (int mi=0; mi<4; ++mi) {
        int ml = wm*64 + mi*16 + quad*4;
        uint2 pk;
        pk.x = pk2(acc[mi][ni][0] + bv, acc[mi][ni][1] + bv);
        pk.y = pk2(acc[mi][ni][2] + bv, acc[mi][ni][3] + bv);
        *(uint2*)&Cs[nl*136 + ml] = pk;
      }
    }
    __syncthreads();
    const int nl = tid >> 1;                 // 0..127
    const int mb = (tid & 1) * 64;           // 0 or 64
    const int h = (n0 + nl) >> 7, dh = (n0 + nl) & 127;
    const int b = m0 >> 11, s0 = m0 & 2047;
    size_t gbase = (((size_t)((b<<3) + h)*128 + dh)*2048) + s0 + mb;
    size_t lbase = (size_t)nl*136 + mb;
#pragma unroll
    for (int j = 0; j < 8; ++j)
      *(uint4*)&out[gbase + j*8] = *(const uint4*)&Cs[lbase + j*8];
  }
}

// ---------------------------------------------------------------------------
// Kernel 2: flash attention — R18: R15 tile (QBLK=128, KVBLK=64, 64KB LDS,
// 32 iters, identical swizzles/staging/grid) but 8 waves/block (512 thr)
// with the KEY dim split across wave pairs: wave (qw=wv&3, kw=wv>>2) owns
// q rows qw*32+[0,32) x keys kw*32+[0,32). Per-CU totals (MFMA, ds bytes,
// exp2) invariant; waves/SIMD 2 -> 4 for latency hiding (R4 post-mortem:
// the wall is dependency stalls, not any pipe; occupancy never changed in
// R17). Inner 32-key loop lifted from the R17 kernel that PASSED on HW.
// One-time epilogue: kw=1 partial O/l reduced into kw=0 via LDS (f32, two
// 40KB rounds), then kw=0 writes O.
// ---------------------------------------------------------------------------
__global__ __launch_bounds__(512, 4) void attn(
    const u16* __restrict__ Qp, const u16* __restrict__ Kp,
    const u16* __restrict__ Vt, u16* __restrict__ O)
{
  __shared__ u16 smem[32768];   // 64KB: Ks0@0, Ks1@8192, Vs0@16384, Vs1@24576

  const int tid = threadIdx.x, wv = tid>>6, lane = tid&63;
  const int l32 = lane&31, h = lane>>5;
  const int qw = wv & 3, kw = wv >> 2;

  // bits [2:0]=xcd, [6:3]=qi, [8:7]=bh-hi: all 16 q-tiles of a bh on one XCD
  const int n  = blockIdx.x;
  const int bh = (n&7)*4 + (n>>7);
  const int q0 = ((n>>3)&15) * 128;

  const u16* Qb = Qp + (size_t)bh*262144 + (size_t)q0*128;
  const u16* Kb = Kp + (size_t)bh*262144;
  const u16* Vb = Vt + (size_t)bh*262144;

  // stage Q tile (128x128, 32KB): 2048 16B-slots, 512 thr -> 4 each
  for (int r = 0; r < 4; ++r) {
    int idx = r*512 + tid;
    int kd = idx>>8, q = (idx>>1)&127, hh = idx&1;
    gl16(Qb + q*128 + kd*16 + hh*8, &smem[idx*8]);
  }
  __syncthreads();
  const int qrow = qw*32 + l32;
  v8s qf[8];
#pragma unroll
  for (int kd = 0; kd < 8; ++kd)
    qf[kd] = *(const v8s*)&smem[kd*2048 + qrow*16 + h*8];
  __syncthreads();   // Q consumed; K/V buffers free

  // hoisted staging offsets with chunk-XOR swizzle (loop-invariant):
  // Ks slot idx -> key=idx>>4, pc=idx&15, src chunk = pc^(key&15)
  // Vs slot idx -> d=idx>>3,  pc=idx&7,  src chunk = pc^(d&7)
  int gK[2], gV[2], lK[2], lV[2];
#pragma unroll
  for (int r = 0; r < 2; ++r) {
    int idx = r*512 + tid;              // 1024 slots each for K and V
    lK[r] = idx*8;  lV[r] = 16384 + idx*8;
    int key = idx>>4, pcK = idx&15;
    gK[r] = key*128 + (pcK ^ (key&15))*8;
    int d = idx>>3, pcV = idx&7;
    gV[r] = d*2048 + (pcV ^ (d&7))*8;
  }
  // per-lane fragment-read chunk offsets (u16 units); kw*32 keys offset:
  // kfo: (kw*32+l32)&15 == l32&15 -> formula unchanged from R15/R17.
  // vfo: global k-chunk = kw*4 + kt*2 + h, swizzle ^ (d&7) with d=nt*32+l32.
  int kfo[8], vfo[2];
#pragma unroll
  for (int kd = 0; kd < 8; ++kd) kfo[kd] = ((kd*2 + h) ^ (l32 & 15)) * 8;
#pragma unroll
  for (int kt = 0; kt < 2; ++kt) vfo[kt] = ((kw*4 + kt*2 + h) ^ (l32 & 7)) * 8;

  const int krow = (kw*32 + l32) * 128;   // K LDS row (u16) for this wave

  v8s onesf;
#pragma unroll
  for (int j = 0; j < 8; ++j) onesf[j] = (short)0x3F80;  // bf16 1.0

  v16f oacc[4], lacc;
#pragma unroll
  for (int nt = 0; nt < 4; ++nt)
#pragma unroll
    for (int j = 0; j < 16; ++j) oacc[nt][j] = 0.f;
#pragma unroll
  for (int j = 0; j < 16; ++j) lacc[j] = 0.f;

  // stage tile 0 into buffer 0
#pragma unroll
  for (int r = 0; r < 2; ++r) gl16(Kb + gK[r], &smem[lK[r]]);
#pragma unroll
  for (int r = 0; r < 2; ++r) gl16(Vb + gV[r], &smem[lV[r]]);

  for (int it = 0; it < 32; ++it) {
    const int cur = it & 1;
    const int ko = cur*8192;            // current Ks base (u16 offset)
    const int vo = 16384 + cur*8192;    // current Vs base
    __syncthreads();   // drains stage(it) + all waves done with buffer cur^1

    if (it + 1 < 32) { // prefetch tile it+1 into the other buffer
      const u16* Kt  = Kb + (it+1)*8192;
      const u16* Vtt = Vb + (it+1)*64;
      const int po = (cur^1)*8192;
#pragma unroll
      for (int r = 0; r < 2; ++r) gl16(Kt  + gK[r], &smem[po + lK[r]]);
#pragma unroll
      for (int r = 0; r < 2; ++r) gl16(Vtt + gV[r], &smem[po + lV[r]]);
    }

    // S^T (32 keys x 32 q per wave) = K * Q^T   (Q pre-scaled by C2)
    v16f sa;
#pragma unroll
    for (int j = 0; j < 16; ++j) sa[j] = 0.f;
    __builtin_amdgcn_s_setprio(1);
#pragma unroll
    for (int kd = 0; kd < 8; ++kd) {
      v8s kf = *(const v8s*)&smem[ko + krow + kfo[kd]];
      sa = MFMA32(kf, qf[kd], sa);
    }
    __builtin_amdgcn_s_setprio(0);

    // P = exp2(sa) packed to bf16 pairs (CB shift cancels in O/l).
    // Own keys (local): key = g*8 + 4h + {0..3}  (regs 4g..4g+3)
    u32 P32[4][2];
#pragma unroll
    for (int g = 0; g < 4; ++g) {
      P32[g][0] = pk2(__builtin_amdgcn_exp2f(sa[g*4+0]),
                      __builtin_amdgcn_exp2f(sa[g*4+1]));
      P32[g][1] = pk2(__builtin_amdgcn_exp2f(sa[g*4+2]),
                      __builtin_amdgcn_exp2f(sa[g*4+3]));
    }

    // Build PV A-frags in regs via lane^32 pair exchange (T12 permlane):
    // r[0]={even.lo,odd.lo}, r[1]={even.hi,odd.hi}.
    v8s pf[2];
#pragma unroll
    for (int kt = 0; kt < 2; ++kt) {
      const int e = kt*2, o = e + 1;
      union { u32 u[4]; v8s s; } f;
#if __has_builtin(__builtin_amdgcn_permlane32_swap)
      v2i r0 = __builtin_amdgcn_permlane32_swap((int)P32[e][0], (int)P32[o][0], false, false);
      v2i r1 = __builtin_amdgcn_permlane32_swap((int)P32[e][1], (int)P32[o][1], false, false);
      f.u[0] = (u32)r0[0]; f.u[1] = (u32)r1[0];
      f.u[2] = (u32)r0[1]; f.u[3] = (u32)r1[1];
#else
      u32 a0 = P32[e][0], b0 = P32[o][0];
      u32 a1 = P32[e][1], b1 = P32[o][1];
      asm("v_permlane32_swap_b32 %0, %1" : "+v"(a0), "+v"(b0));
      asm("v_permlane32_swap_b32 %0, %1" : "+v"(a1), "+v"(b1));
      f.u[0] = a0; f.u[1] = a1; f.u[2] = b0; f.u[3] = b1;
#endif
      pf[kt] = f.s;
    }

    // O(32q x 128d) += P(32q x 32k) @ V(32k x 128d);  l += P @ ones
    __builtin_amdgcn_s_setprio(1);
#pragma unroll
    for (int kt = 0; kt < 2; ++kt) {
      lacc = MFMA32(pf[kt], onesf, lacc);
#pragma unroll
      for (int nt = 0; nt < 4; ++nt) {
        v8s vf = *(const v8s*)&smem[vo + (nt*32 + l32)*64 + vfo[kt]];
        oacc[nt] = MFMA32(pf[kt], vf, oacc[nt]);
      }
    }
    __builtin_amdgcn_s_setprio(0);
  }

  // Cross-wave reduce: kw=1 partials into kw=0, via LDS f32, two 40KB rounds
  // (qw pairs {0,1} then {2,3}). Layout per (qw&1): 32 rows x 160 f32
  // (128 O-d slots + 32 replicated-l slots).
  {
    float* red = (float*)smem;
    for (int round = 0; round < 2; ++round) {
      __syncthreads();
      if ((qw >> 1) == round && kw == 1) {
        const int base = (qw & 1) * 5120;
#pragma unroll
        for (int reg = 0; reg < 16; ++reg) {
          int row = (reg&3) + 8*(reg>>2) + 4*h;
#pragma unroll
          for (int nt = 0; nt < 4; ++nt)
            red[base + row*160 + nt*32 + l32] = oacc[nt][reg];
          red[base + row*160 + 128 + l32] = lacc[reg];  // same value all lanes
        }
      }
      __syncthreads();
      if ((qw >> 1) == round && kw == 0) {
        const int base = (qw & 1) * 5120;
#pragma unroll
        for (int reg = 0; reg < 16; ++reg) {
          int row = (reg&3) + 8*(reg>>2) + 4*h;
#pragma unroll
          for (int nt = 0; nt < 4; ++nt)
            oacc[nt][reg] += red[base + row*160 + nt*32 + l32];
          lacc[reg] += red[base + row*160 + 128 + l32];
        }
      }
    }
  }

  if (kw == 0) {
    const int b = bh >> 3, hd = bh & 7;
#pragma unroll
    for (int reg = 0; reg < 16; ++reg) {
      int q = q0 + qw*32 + (reg&3) + 8*(reg>>2) + 4*h;
      float inv = 1.0f / lacc[reg];
      size_t base = ((size_t)(b*2048 + q))*1024 + hd*128;
#pragma unroll
      for (int nt = 0; nt < 4; ++nt)
        O[base + nt*32 + l32] = f2b(oacc[nt][reg] * inv);
    }
  }
}

// ---------------------------------------------------------------------------
// Kernel 3: output projection (R16 double-buffered version, unchanged).
// ---------------------------------------------------------------------------
__global__ __launch_bounds__(256) void outproj(
    const u16* __restrict__ A, const float* __restrict__ Ww,
    const float* __restrict__ Wb, float* __restrict__ out)
{
  __shared__ u16 As[2][2048];  // [buf][2 kt][32 m][32 k]
  __shared__ u16 Ws[2][8192];  // [buf][2 kt][128 n][32 k]

  const int tid = threadIdx.x, wv = tid>>6, lane = tid&63;
  const int quad = lane>>4, l16 = lane&15;
  const int r4 = lane>>2, c4 = lane&3;
  const int m0 = blockIdx.x*32;

  v4f acc[2][2];   // [mi][nj], nt = wv*2 + nj
#pragma unroll
  for (int i=0;i<2;i++)
#pragma unroll
    for (int j=0;j<2;j++) acc[i][j] = (v4f){0.f,0.f,0.f,0.f};

  // stage chunk kb into buffer buf
  auto stage = [&](int kb, int buf) {
    {  // A tile: 4 regions, one per wave (bf16 internal -> gl16)
      int kt = wv >> 1, rg = wv & 1;
      int row = rg*16 + r4;
      gl16(A + (size_t)(m0+row)*1024 + kb + kt*32 + c4*8, &As[buf][kt*1024 + rg*512 + lane*8]);
    }
    for (int idx = wv; idx < 16; idx += 4) {   // W tile: fp32 -> bf16 staging
      int kt = idx >> 3, rg = idx & 7;
      int row = rg*16 + r4;
      stage8f(Ww + (size_t)row*1024 + kb + kt*32 + c4*8, &Ws[buf][kt*4096 + rg*512 + lane*8]);
    }
  };

  stage(0, 0);
  for (int kb = 0; kb < 1024; kb += 64) {
    const int cur = (kb >> 6) & 1;
    __syncthreads();   // drains stage(kb) + all waves done reading buf cur^1
    if (kb + 64 < 1024) stage(kb + 64, cur ^ 1);
#pragma unroll
    for (int ks = 0; ks < 2; ++ks) {
      v8s af0 = *(const v8s*)&As[cur][ks*1024 + (l16)*32 + quad*8];
      v8s af1 = *(const v8s*)&As[cur][ks*1024 + (16 + l16)*32 + quad*8];
#pragma unroll
      for (int nj = 0; nj < 2; ++nj) {
        v8s bf = *(const v8s*)&Ws[cur][ks*4096 + ((wv*2+nj)*16 + l16)*32 + quad*8];
        acc[0][nj] = MFMA16(af0, bf, acc[0][nj]);
        acc[1][nj] = MFMA16(af1, bf, acc[1][nj]);
      }
    }
  }

#pragma unroll
  for (int nj = 0; nj < 2; ++nj) {
    int col = (wv*2+nj)*16 + l16;
    float bv = Wb[col];
#pragma unroll
    for (int mi = 0; mi < 2; ++mi) {
#pragma unroll
      for (int r = 0; r < 4; ++r) {
        int row = m0 + mi*16 + quad*4 + r;
        out[(size_t)row*128 + col] = acc[mi][nj][r] + bv;
      }
    }
  }
}

// ---------------------------------------------------------------------------
extern "C" void kernel_launch(void* const* d_in, const int* in_sizes, int n_in,
                              void* d_out, int out_size, void* d_ws, size_t ws_size,
                              hipStream_t stream) {
  const float* Q   = (const float*)d_in[0];
  const float* K   = (const float*)d_in[1];
  const float* V   = (const float*)d_in[2];
  const float* WQw = (const float*)d_in[3];
  const float* WQb = (const float*)d_in[4];
  const float* WKw = (const float*)d_in[5];
  const float* WKb = (const float*)d_in[6];
  const float* WVw = (const float*)d_in[7];
  const float* WVb = (const float*)d_in[8];
  const float* Ww  = (const float*)d_in[9];
  const float* Wb  = (const float*)d_in[10];
  u16* ws = (u16*)d_ws;

  const size_t SZ = (size_t)4*8*2048*128;    // 8,388,608 elems per tensor
  u16* Qp = ws;
  u16* Kp = Qp + SZ;
  u16* Vt = Kp + SZ;
  u16* Ow = Vt + SZ;

  hipLaunchKernelGGL(proj_qkv, dim3(64,8,3), dim3(256), 0, stream,
                     Q,K,V,WQw,WQb,WKw,WKb,WVw,WVb,Qp,Kp,Vt);
  hipLaunchKernelGGL(attn, dim3(512), dim3(512), 0, stream, Qp,Kp,Vt,Ow);
  hipLaunchKernelGGL(outproj, dim3(256), dim3(256), 0, stream, Ow, Ww, Wb, (float*)d_out);
}

// Round 6
// 212.842 us; speedup vs baseline: 1.5640x; 1.5640x over previous
//
#include <hip/hip_runtime.h>
#include <hip/hip_bf16.h>

typedef unsigned short u16;
typedef unsigned int   u32;
typedef short v8s __attribute__((ext_vector_type(8)));
typedef float v4f __attribute__((ext_vector_type(4)));
typedef float v16f __attribute__((ext_vector_type(16)));
typedef int   v2i __attribute__((ext_vector_type(2)));

#define MFMA16(a,b,c) __builtin_amdgcn_mfma_f32_16x16x32_bf16(a,b,c,0,0,0)
#define MFMA32(a,b,c) __builtin_amdgcn_mfma_f32_32x32x16_bf16(a,b,c,0,0,0)

// Harness I/O dtype is FP32 (confirmed R11-R13 bisect). Internals bf16.
// Softmax scale C2 folded into Qp at proj; CB shift cancels in O/l.

__device__ __forceinline__ u16 f2b(float f){ u32 i; __builtin_memcpy(&i,&f,4); u32 r = (i + 0x7FFFu + ((i>>16)&1u))>>16; return (u16)r; }
__device__ __forceinline__ u32 pk2(float a, float b){
  __hip_bfloat162 h = __float22bfloat162_rn(make_float2(a,b));
  u32 r; __builtin_memcpy(&r,&h,4); return r;
}

// async global->LDS DMA, 16B per lane (bf16 sources only).
__device__ __forceinline__ void gl16(const void* g, void* l){
  __builtin_amdgcn_global_load_lds((const __attribute__((address_space(1))) u32*)g,
                                   (__attribute__((address_space(3))) u32*)l, 16, 0, 0);
}

// fp32 staging: 8 f32 -> 8 bf16 into LDS via packed v_cvt_pk_bf16_f32
__device__ __forceinline__ void stage8f(const float* g, u16* l){
  float4 a = *(const float4*)g, b = *(const float4*)(g+4);
  uint4 q;
  q.x = pk2(a.x, a.y); q.y = pk2(a.z, a.w);
  q.z = pk2(b.x, b.y); q.w = pk2(b.z, b.w);
  *(uint4*)l = q;
}

// ---------------------------------------------------------------------------
// Kernel 1: fused QKV projection (R15, unchanged). Inputs fp32, internals bf16.
// z=0: Qp[B,H,S,D] (PRE-SCALED by C2), z=1: Kp, z=2: Vt[B,H,D,S] transpose.
// ---------------------------------------------------------------------------
__global__ __launch_bounds__(256) void proj_qkv(
    const float* __restrict__ Qx, const float* __restrict__ Kx, const float* __restrict__ Vx,
    const float* __restrict__ WQw, const float* __restrict__ WQb,
    const float* __restrict__ WKw, const float* __restrict__ WKb,
    const float* __restrict__ WVw, const float* __restrict__ WVb,
    u16* __restrict__ Qp, u16* __restrict__ Kp, u16* __restrict__ Vt)
{
  __shared__ u16 smem[32768];          // As(16384) + Ws(16384); reused as Cs
  u16* As = smem;
  u16* Ws = smem + 16384;

  const int z = blockIdx.z;
  const float* X    = (z==0) ? Qx  : (z==1 ? Kx  : Vx);
  const float* W    = (z==0) ? WQw : (z==1 ? WKw : WVw);
  const float* bias = (z==0) ? WQb : (z==1 ? WKb : WVb);
  u16* out          = (z==0) ? Qp  : (z==1 ? Kp  : Vt);
  const float qs    = (z==0) ? 0.12751743076f : 1.0f;   // C2 fold into Q

  const int tid = threadIdx.x, wv = tid>>6, lane = tid&63;
  const int quad = lane>>4, l16 = lane&15;
  const int r4 = lane>>2, c4 = lane&3;
  const int m0 = blockIdx.x*128, n0 = blockIdx.y*128;

  for (int idx = wv; idx < 32; idx += 4) {
    int kt = idx >> 3, rg = idx & 7;
    int row = rg*16 + r4;
    stage8f(X + (size_t)(m0+row)*128 + kt*32 + c4*8, &As[kt*4096 + rg*512 + lane*8]);
    stage8f(W + (size_t)(n0+row)*128 + kt*32 + c4*8, &Ws[kt*4096 + rg*512 + lane*8]);
  }
  __syncthreads();

  const int wm = wv & 1, wn = wv >> 1;
  v4f acc[4][4];
#pragma unroll
  for (int i=0;i<4;i++)
#pragma unroll
    for (int j=0;j<4;j++) acc[i][j] = (v4f){0.f,0.f,0.f,0.f};

  if (z < 2) {
#pragma unroll
    for (int ks=0; ks<4; ++ks) {
      v8s af[4], bf[4];
#pragma unroll
      for (int mi=0; mi<4; ++mi) af[mi] = *(const v8s*)&As[ks*4096 + (wm*64+mi*16+l16)*32 + quad*8];
#pragma unroll
      for (int ni=0; ni<4; ++ni) bf[ni] = *(const v8s*)&Ws[ks*4096 + (wn*64+ni*16+l16)*32 + quad*8];
#pragma unroll
      for (int mi=0; mi<4; ++mi)
#pragma unroll
        for (int ni=0; ni<4; ++ni)
          acc[mi][ni] = MFMA16(bf[ni], af[mi], acc[mi][ni]);   // A=W, B=X
    }
#pragma unroll
    for (int ni=0; ni<4; ++ni) {
      int nb = n0 + wn*64 + ni*16 + quad*4;   // global n, 4 consecutive (r)
      float bv0 = bias[nb+0]*qs;
      float bv1 = bias[nb+1]*qs;
      float bv2 = bias[nb+2]*qs;
      float bv3 = bias[nb+3]*qs;
      int h = n0 >> 7, dh = nb & 127;
#pragma unroll
      for (int mi=0; mi<4; ++mi) {
        int m = m0 + wm*64 + mi*16 + l16;
        int b = m >> 11, s = m & 2047;
        uint2 pk;
        pk.x = pk2(fmaf(acc[mi][ni][0], qs, bv0), fmaf(acc[mi][ni][1], qs, bv1));
        pk.y = pk2(fmaf(acc[mi][ni][2], qs, bv2), fmaf(acc[mi][ni][3], qs, bv3));
        *(uint2*)&out[(size_t)(((b<<3) + h)*2048 + s)*128 + dh] = pk;
      }
    }
  } else {
#pragma unroll
    for (int ks=0; ks<4; ++ks) {
      v8s af[4], bf[4];
#pragma unroll
      for (int mi=0; mi<4; ++mi) af[mi] = *(const v8s*)&As[ks*4096 + (wm*64+mi*16+l16)*32 + quad*8];
#pragma unroll
      for (int ni=0; ni<4; ++ni) bf[ni] = *(const v8s*)&Ws[ks*4096 + (wn*64+ni*16+l16)*32 + quad*8];
#pragma unroll
      for (int mi=0; mi<4; ++mi)
#pragma unroll
        for (int ni=0; ni<4; ++ni)
          acc[mi][ni] = MFMA16(af[mi], bf[ni], acc[mi][ni]);
    }
    __syncthreads();               // all waves done reading As/Ws
    u16* Cs = smem;                // Cs[n][136]
#pragma unroll
    for (int ni=0; ni<4; ++ni) {
      int nl = wn*64 + ni*16 + l16;
      float bv = bias[n0 + nl];
#pragma unroll
      for (int mi=0; mi<4; ++mi) {
        int ml = wm*64 + mi*16 + quad*4;
        uint2 pk;
        pk.x = pk2(acc[mi][ni][0] + bv, acc[mi][ni][1] + bv);
        pk.y = pk2(acc[mi][ni][2] + bv, acc[mi][ni][3] + bv);
        *(uint2*)&Cs[nl*136 + ml] = pk;
      }
    }
    __syncthreads();
    const int nl = tid >> 1;                 // 0..127
    const int mb = (tid & 1) * 64;           // 0 or 64
    const int h = (n0 + nl) >> 7, dh = (n0 + nl) & 127;
    const int b = m0 >> 11, s0 = m0 & 2047;
    size_t gbase = (((size_t)((b<<3) + h)*128 + dh)*2048) + s0 + mb;
    size_t lbase = (size_t)nl*136 + mb;
#pragma unroll
    for (int j = 0; j < 8; ++j)
      *(uint4*)&out[gbase + j*8] = *(const uint4*)&Cs[lbase + j*8];
  }
}

// ---------------------------------------------------------------------------
// Kernel 2: flash attention — R19 = R18 structure with the spill fixed.
// R18 post-mortem: __launch_bounds__(512,4) forced VGPR_Count=64 < the ~112
// regs of live state (oacc 64 + lacc 16 + qf 32) -> scratch spill -> FETCH
// 24.6MB -> 550MB, HBM 2.9TB/s of spill traffic, 212µs. The occupancy goal
// itself WAS reached (45%). Fix: __launch_bounds__(512, 2) -> VGPR cap 256;
// expected alloc ~88-120 (R17 compiled identical per-wave state to 88).
// Residency: LDS 64KB -> 2 blocks/CU = 16 waves/CU = 4 waves/SIMD (VGPR pool
// 2048/SIMD / ~100 = 5 waves, not binding). Everything else frozen vs R18.
// ---------------------------------------------------------------------------
__global__ __launch_bounds__(512, 2) void attn(
    const u16* __restrict__ Qp, const u16* __restrict__ Kp,
    const u16* __restrict__ Vt, u16* __restrict__ O)
{
  __shared__ u16 smem[32768];   // 64KB: Ks0@0, Ks1@8192, Vs0@16384, Vs1@24576

  const int tid = threadIdx.x, wv = tid>>6, lane = tid&63;
  const int l32 = lane&31, h = lane>>5;
  const int qw = wv & 3, kw = wv >> 2;

  // bits [2:0]=xcd, [6:3]=qi, [8:7]=bh-hi: all 16 q-tiles of a bh on one XCD
  const int n  = blockIdx.x;
  const int bh = (n&7)*4 + (n>>7);
  const int q0 = ((n>>3)&15) * 128;

  const u16* Qb = Qp + (size_t)bh*262144 + (size_t)q0*128;
  const u16* Kb = Kp + (size_t)bh*262144;
  const u16* Vb = Vt + (size_t)bh*262144;

  // stage Q tile (128x128, 32KB): 2048 16B-slots, 512 thr -> 4 each
  for (int r = 0; r < 4; ++r) {
    int idx = r*512 + tid;
    int kd = idx>>8, q = (idx>>1)&127, hh = idx&1;
    gl16(Qb + q*128 + kd*16 + hh*8, &smem[idx*8]);
  }
  __syncthreads();
  const int qrow = qw*32 + l32;
  v8s qf[8];
#pragma unroll
  for (int kd = 0; kd < 8; ++kd)
    qf[kd] = *(const v8s*)&smem[kd*2048 + qrow*16 + h*8];
  __syncthreads();   // Q consumed; K/V buffers free

  // hoisted staging offsets with chunk-XOR swizzle (loop-invariant):
  // Ks slot idx -> key=idx>>4, pc=idx&15, src chunk = pc^(key&15)
  // Vs slot idx -> d=idx>>3,  pc=idx&7,  src chunk = pc^(d&7)
  int gK[2], gV[2], lK[2], lV[2];
#pragma unroll
  for (int r = 0; r < 2; ++r) {
    int idx = r*512 + tid;              // 1024 slots each for K and V
    lK[r] = idx*8;  lV[r] = 16384 + idx*8;
    int key = idx>>4, pcK = idx&15;
    gK[r] = key*128 + (pcK ^ (key&15))*8;
    int d = idx>>3, pcV = idx&7;
    gV[r] = d*2048 + (pcV ^ (d&7))*8;
  }
  // per-lane fragment-read chunk offsets (u16 units); kw*32 keys offset:
  // kfo: (kw*32+l32)&15 == l32&15 -> formula unchanged from R15/R17.
  // vfo: global k-chunk = kw*4 + kt*2 + h, swizzle ^ (d&7) with d=nt*32+l32.
  int kfo[8], vfo[2];
#pragma unroll
  for (int kd = 0; kd < 8; ++kd) kfo[kd] = ((kd*2 + h) ^ (l32 & 15)) * 8;
#pragma unroll
  for (int kt = 0; kt < 2; ++kt) vfo[kt] = ((kw*4 + kt*2 + h) ^ (l32 & 7)) * 8;

  const int krow = (kw*32 + l32) * 128;   // K LDS row (u16) for this wave

  v8s onesf;
#pragma unroll
  for (int j = 0; j < 8; ++j) onesf[j] = (short)0x3F80;  // bf16 1.0

  v16f oacc[4], lacc;
#pragma unroll
  for (int nt = 0; nt < 4; ++nt)
#pragma unroll
    for (int j = 0; j < 16; ++j) oacc[nt][j] = 0.f;
#pragma unroll
  for (int j = 0; j < 16; ++j) lacc[j] = 0.f;

  // stage tile 0 into buffer 0
#pragma unroll
  for (int r = 0; r < 2; ++r) gl16(Kb + gK[r], &smem[lK[r]]);
#pragma unroll
  for (int r = 0; r < 2; ++r) gl16(Vb + gV[r], &smem[lV[r]]);

  for (int it = 0; it < 32; ++it) {
    const int cur = it & 1;
    const int ko = cur*8192;            // current Ks base (u16 offset)
    const int vo = 16384 + cur*8192;    // current Vs base
    __syncthreads();   // drains stage(it) + all waves done with buffer cur^1

    if (it + 1 < 32) { // prefetch tile it+1 into the other buffer
      const u16* Kt  = Kb + (it+1)*8192;
      const u16* Vtt = Vb + (it+1)*64;
      const int po = (cur^1)*8192;
#pragma unroll
      for (int r = 0; r < 2; ++r) gl16(Kt  + gK[r], &smem[po + lK[r]]);
#pragma unroll
      for (int r = 0; r < 2; ++r) gl16(Vtt + gV[r], &smem[po + lV[r]]);
    }

    // S^T (32 keys x 32 q per wave) = K * Q^T   (Q pre-scaled by C2)
    v16f sa;
#pragma unroll
    for (int j = 0; j < 16; ++j) sa[j] = 0.f;
    __builtin_amdgcn_s_setprio(1);
#pragma unroll
    for (int kd = 0; kd < 8; ++kd) {
      v8s kf = *(const v8s*)&smem[ko + krow + kfo[kd]];
      sa = MFMA32(kf, qf[kd], sa);
    }
    __builtin_amdgcn_s_setprio(0);

    // P = exp2(sa) packed to bf16 pairs (CB shift cancels in O/l).
    // Own keys (local): key = g*8 + 4h + {0..3}  (regs 4g..4g+3)
    u32 P32[4][2];
#pragma unroll
    for (int g = 0; g < 4; ++g) {
      P32[g][0] = pk2(__builtin_amdgcn_exp2f(sa[g*4+0]),
                      __builtin_amdgcn_exp2f(sa[g*4+1]));
      P32[g][1] = pk2(__builtin_amdgcn_exp2f(sa[g*4+2]),
                      __builtin_amdgcn_exp2f(sa[g*4+3]));
    }

    // Build PV A-frags in regs via lane^32 pair exchange (T12 permlane):
    // r[0]={even.lo,odd.lo}, r[1]={even.hi,odd.hi}.
    v8s pf[2];
#pragma unroll
    for (int kt = 0; kt < 2; ++kt) {
      const int e = kt*2, o = e + 1;
      union { u32 u[4]; v8s s; } f;
#if __has_builtin(__builtin_amdgcn_permlane32_swap)
      v2i r0 = __builtin_amdgcn_permlane32_swap((int)P32[e][0], (int)P32[o][0], false, false);
      v2i r1 = __builtin_amdgcn_permlane32_swap((int)P32[e][1], (int)P32[o][1], false, false);
      f.u[0] = (u32)r0[0]; f.u[1] = (u32)r1[0];
      f.u[2] = (u32)r0[1]; f.u[3] = (u32)r1[1];
#else
      u32 a0 = P32[e][0], b0 = P32[o][0];
      u32 a1 = P32[e][1], b1 = P32[o][1];
      asm("v_permlane32_swap_b32 %0, %1" : "+v"(a0), "+v"(b0));
      asm("v_permlane32_swap_b32 %0, %1" : "+v"(a1), "+v"(b1));
      f.u[0] = a0; f.u[1] = a1; f.u[2] = b0; f.u[3] = b1;
#endif
      pf[kt] = f.s;
    }

    // O(32q x 128d) += P(32q x 32k) @ V(32k x 128d);  l += P @ ones
    __builtin_amdgcn_s_setprio(1);
#pragma unroll
    for (int kt = 0; kt < 2; ++kt) {
      lacc = MFMA32(pf[kt], onesf, lacc);
#pragma unroll
      for (int nt = 0; nt < 4; ++nt) {
        v8s vf = *(const v8s*)&smem[vo + (nt*32 + l32)*64 + vfo[kt]];
        oacc[nt] = MFMA32(pf[kt], vf, oacc[nt]);
      }
    }
    __builtin_amdgcn_s_setprio(0);
  }

  // Cross-wave reduce: kw=1 partials into kw=0, via LDS f32, two 40KB rounds
  // (qw pairs {0,1} then {2,3}). Layout per (qw&1): 32 rows x 160 f32
  // (128 O-d slots + 32 replicated-l slots).
  {
    float* red = (float*)smem;
    for (int round = 0; round < 2; ++round) {
      __syncthreads();
      if ((qw >> 1) == round && kw == 1) {
        const int base = (qw & 1) * 5120;
#pragma unroll
        for (int reg = 0; reg < 16; ++reg) {
          int row = (reg&3) + 8*(reg>>2) + 4*h;
#pragma unroll
          for (int nt = 0; nt < 4; ++nt)
            red[base + row*160 + nt*32 + l32] = oacc[nt][reg];
          red[base + row*160 + 128 + l32] = lacc[reg];  // same value all lanes
        }
      }
      __syncthreads();
      if ((qw >> 1) == round && kw == 0) {
        const int base = (qw & 1) * 5120;
#pragma unroll
        for (int reg = 0; reg < 16; ++reg) {
          int row = (reg&3) + 8*(reg>>2) + 4*h;
#pragma unroll
          for (int nt = 0; nt < 4; ++nt)
            oacc[nt][reg] += red[base + row*160 + nt*32 + l32];
          lacc[reg] += red[base + row*160 + 128 + l32];
        }
      }
    }
  }

  if (kw == 0) {
    const int b = bh >> 3, hd = bh & 7;
#pragma unroll
    for (int reg = 0; reg < 16; ++reg) {
      int q = q0 + qw*32 + (reg&3) + 8*(reg>>2) + 4*h;
      float inv = 1.0f / lacc[reg];
      size_t base = ((size_t)(b*2048 + q))*1024 + hd*128;
#pragma unroll
      for (int nt = 0; nt < 4; ++nt)
        O[base + nt*32 + l32] = f2b(oacc[nt][reg] * inv);
    }
  }
}

// ---------------------------------------------------------------------------
// Kernel 3: output projection (R16 double-buffered version, unchanged).
// ---------------------------------------------------------------------------
__global__ __launch_bounds__(256) void outproj(
    const u16* __restrict__ A, const float* __restrict__ Ww,
    const float* __restrict__ Wb, float* __restrict__ out)
{
  __shared__ u16 As[2][2048];  // [buf][2 kt][32 m][32 k]
  __shared__ u16 Ws[2][8192];  // [buf][2 kt][128 n][32 k]

  const int tid = threadIdx.x, wv = tid>>6, lane = tid&63;
  const int quad = lane>>4, l16 = lane&15;
  const int r4 = lane>>2, c4 = lane&3;
  const int m0 = blockIdx.x*32;

  v4f acc[2][2];   // [mi][nj], nt = wv*2 + nj
#pragma unroll
  for (int i=0;i<2;i++)
#pragma unroll
    for (int j=0;j<2;j++) acc[i][j] = (v4f){0.f,0.f,0.f,0.f};

  // stage chunk kb into buffer buf
  auto stage = [&](int kb, int buf) {
    {  // A tile: 4 regions, one per wave (bf16 internal -> gl16)
      int kt = wv >> 1, rg = wv & 1;
      int row = rg*16 + r4;
      gl16(A + (size_t)(m0+row)*1024 + kb + kt*32 + c4*8, &As[buf][kt*1024 + rg*512 + lane*8]);
    }
    for (int idx = wv; idx < 16; idx += 4) {   // W tile: fp32 -> bf16 staging
      int kt = idx >> 3, rg = idx & 7;
      int row = rg*16 + r4;
      stage8f(Ww + (size_t)row*1024 + kb + kt*32 + c4*8, &Ws[buf][kt*4096 + rg*512 + lane*8]);
    }
  };

  stage(0, 0);
  for (int kb = 0; kb < 1024; kb += 64) {
    const int cur = (kb >> 6) & 1;
    __syncthreads();   // drains stage(kb) + all waves done reading buf cur^1
    if (kb + 64 < 1024) stage(kb + 64, cur ^ 1);
#pragma unroll
    for (int ks = 0; ks < 2; ++ks) {
      v8s af0 = *(const v8s*)&As[cur][ks*1024 + (l16)*32 + quad*8];
      v8s af1 = *(const v8s*)&As[cur][ks*1024 + (16 + l16)*32 + quad*8];
#pragma unroll
      for (int nj = 0; nj < 2; ++nj) {
        v8s bf = *(const v8s*)&Ws[cur][ks*4096 + ((wv*2+nj)*16 + l16)*32 + quad*8];
        acc[0][nj] = MFMA16(af0, bf, acc[0][nj]);
        acc[1][nj] = MFMA16(af1, bf, acc[1][nj]);
      }
    }
  }

#pragma unroll
  for (int nj = 0; nj < 2; ++nj) {
    int col = (wv*2+nj)*16 + l16;
    float bv = Wb[col];
#pragma unroll
    for (int mi = 0; mi < 2; ++mi) {
#pragma unroll
      for (int r = 0; r < 4; ++r) {
        int row = m0 + mi*16 + quad*4 + r;
        out[(size_t)row*128 + col] = acc[mi][nj][r] + bv;
      }
    }
  }
}

// ---------------------------------------------------------------------------
extern "C" void kernel_launch(void* const* d_in, const int* in_sizes, int n_in,
                              void* d_out, int out_size, void* d_ws, size_t ws_size,
                              hipStream_t stream) {
  const float* Q   = (const float*)d_in[0];
  const float* K   = (const float*)d_in[1];
  const float* V   = (const float*)d_in[2];
  const float* WQw = (const float*)d_in[3];
  const float* WQb = (const float*)d_in[4];
  const float* WKw = (const float*)d_in[5];
  const float* WKb = (const float*)d_in[6];
  const float* WVw = (const float*)d_in[7];
  const float* WVb = (const float*)d_in[8];
  const float* Ww  = (const float*)d_in[9];
  const float* Wb  = (const float*)d_in[10];
  u16* ws = (u16*)d_ws;

  const size_t SZ = (size_t)4*8*2048*128;    // 8,388,608 elems per tensor
  u16* Qp = ws;
  u16* Kp = Qp + SZ;
  u16* Vt = Kp + SZ;
  u16* Ow = Vt + SZ;

  hipLaunchKernelGGL(proj_qkv, dim3(64,8,3), dim3(256), 0, stream,
                     Q,K,V,WQw,WQb,WKw,WKb,WVw,WVb,Qp,Kp,Vt);
  hipLaunchKernelGGL(attn, dim3(512), dim3(512), 0, stream, Qp,Kp,Vt,Ow);
  hipLaunchKernelGGL(outproj, dim3(256), dim3(256), 0, stream, Ow, Ww, Wb, (float*)d_out);
}

// Round 8
// 211.473 us; speedup vs baseline: 1.5742x; 1.0065x over previous
//
#include <hip/hip_runtime.h>
#include <hip/hip_bf16.h>

typedef unsigned short u16;
typedef unsigned int   u32;
typedef short v8s __attribute__((ext_vector_type(8)));
typedef float v4f __attribute__((ext_vector_type(4)));
typedef float v16f __attribute__((ext_vector_type(16)));
typedef int   v2i __attribute__((ext_vector_type(2)));

#define MFMA16(a,b,c) __builtin_amdgcn_mfma_f32_16x16x32_bf16(a,b,c,0,0,0)
#define MFMA32(a,b,c) __builtin_amdgcn_mfma_f32_32x32x16_bf16(a,b,c,0,0,0)

// Harness I/O dtype is FP32 (confirmed R11-R13 bisect). Internals bf16.
// Softmax scale C2 folded into Qp at proj; CB shift cancels in O/l.

__device__ __forceinline__ u16 f2b(float f){ u32 i; __builtin_memcpy(&i,&f,4); u32 r = (i + 0x7FFFu + ((i>>16)&1u))>>16; return (u16)r; }
__device__ __forceinline__ u32 pk2(float a, float b){
  __hip_bfloat162 h = __float22bfloat162_rn(make_float2(a,b));
  u32 r; __builtin_memcpy(&r,&h,4); return r;
}

// async global->LDS DMA, 16B per lane (bf16 sources only).
__device__ __forceinline__ void gl16(const void* g, void* l){
  __builtin_amdgcn_global_load_lds((const __attribute__((address_space(1))) u32*)g,
                                   (__attribute__((address_space(3))) u32*)l, 16, 0, 0);
}

// fp32 staging: 8 f32 -> 8 bf16 into LDS via packed v_cvt_pk_bf16_f32
__device__ __forceinline__ void stage8f(const float* g, u16* l){
  float4 a = *(const float4*)g, b = *(const float4*)(g+4);
  uint4 q;
  q.x = pk2(a.x, a.y); q.y = pk2(a.z, a.w);
  q.z = pk2(b.x, b.y); q.w = pk2(b.z, b.w);
  *(uint4*)l = q;
}

// ---------------------------------------------------------------------------
// Kernel 1: fused QKV projection. R20: z<2 epilogue was the last uncoalesced
// path — 16 uint2 stores/wave at 256B lane stride (8B used per 64B line, 8x
// write-transaction inflation on 32MB of z0+z1 output). Now staged through
// LDS (Cs[128 m][136], bias+qs folded at Cs-write) and written out linearly:
// each store instr = 64 lanes x 16B fully contiguous (1KB/instr) into the
// contiguous 32KB (b,h,s0..s0+127) output tile. z=2 path already did the
// LDS-transpose trick and is unchanged.
// ---------------------------------------------------------------------------
__global__ __launch_bounds__(256) void proj_qkv(
    const float* __restrict__ Qx, const float* __restrict__ Kx, const float* __restrict__ Vx,
    const float* __restrict__ WQw, const float* __restrict__ WQb,
    const float* __restrict__ WKw, const float* __restrict__ WKb,
    const float* __restrict__ WVw, const float* __restrict__ WVb,
    u16* __restrict__ Qp, u16* __restrict__ Kp, u16* __restrict__ Vt)
{
  __shared__ u16 smem[32768];          // As(16384) + Ws(16384); reused as Cs
  u16* As = smem;
  u16* Ws = smem + 16384;

  const int z = blockIdx.z;
  const float* X    = (z==0) ? Qx  : (z==1 ? Kx  : Vx);
  const float* W    = (z==0) ? WQw : (z==1 ? WKw : WVw);
  const float* bias = (z==0) ? WQb : (z==1 ? WKb : WVb);
  u16* out          = (z==0) ? Qp  : (z==1 ? Kp  : Vt);
  const float qs    = (z==0) ? 0.12751743076f : 1.0f;   // C2 fold into Q

  const int tid = threadIdx.x, wv = tid>>6, lane = tid&63;
  const int quad = lane>>4, l16 = lane&15;
  const int r4 = lane>>2, c4 = lane&3;
  const int m0 = blockIdx.x*128, n0 = blockIdx.y*128;

  for (int idx = wv; idx < 32; idx += 4) {
    int kt = idx >> 3, rg = idx & 7;
    int row = rg*16 + r4;
    stage8f(X + (size_t)(m0+row)*128 + kt*32 + c4*8, &As[kt*4096 + rg*512 + lane*8]);
    stage8f(W + (size_t)(n0+row)*128 + kt*32 + c4*8, &Ws[kt*4096 + rg*512 + lane*8]);
  }
  __syncthreads();

  const int wm = wv & 1, wn = wv >> 1;
  v4f acc[4][4];
#pragma unroll
  for (int i=0;i<4;i++)
#pragma unroll
    for (int j=0;j<4;j++) acc[i][j] = (v4f){0.f,0.f,0.f,0.f};

  if (z < 2) {
#pragma unroll
    for (int ks=0; ks<4; ++ks) {
      v8s af[4], bf[4];
#pragma unroll
      for (int mi=0; mi<4; ++mi) af[mi] = *(const v8s*)&As[ks*4096 + (wm*64+mi*16+l16)*32 + quad*8];
#pragma unroll
      for (int ni=0; ni<4; ++ni) bf[ni] = *(const v8s*)&Ws[ks*4096 + (wn*64+ni*16+l16)*32 + quad*8];
#pragma unroll
      for (int mi=0; mi<4; ++mi)
#pragma unroll
        for (int ni=0; ni<4; ++ni)
          acc[mi][ni] = MFMA16(bf[ni], af[mi], acc[mi][ni]);   // A=W, B=X
    }
    __syncthreads();               // As/Ws consumed; smem free for Cs
    u16* Cs = smem;                // Cs[m-local 128][136]
    // acc[mi][ni][r]: m = m0+wm*64+mi*16+l16 (C col), n = n0+wn*64+ni*16+quad*4+r (C row)
#pragma unroll
    for (int ni=0; ni<4; ++ni) {
      int nl = wn*64 + ni*16 + quad*4;        // d-local, 4 consecutive (r)
      int nb = n0 + nl;
      float bv0 = bias[nb+0]*qs;
      float bv1 = bias[nb+1]*qs;
      float bv2 = bias[nb+2]*qs;
      float bv3 = bias[nb+3]*qs;
#pragma unroll
      for (int mi=0; mi<4; ++mi) {
        int ml = wm*64 + mi*16 + l16;         // m-local
        uint2 pk;
        pk.x = pk2(fmaf(acc[mi][ni][0], qs, bv0), fmaf(acc[mi][ni][1], qs, bv1));
        pk.y = pk2(fmaf(acc[mi][ni][2], qs, bv2), fmaf(acc[mi][ni][3], qs, bv3));
        *(uint2*)&Cs[ml*136 + nl] = pk;
      }
    }
    __syncthreads();
    // coalesced writeout: 32KB tile image is contiguous in global:
    // rows = s0..s0+127 (m0 within one b: 2048 % 128 == 0), cols = dh 0..127.
    const int h = n0 >> 7;
    const int b = m0 >> 11, s0 = m0 & 2047;
    u16* gout = out + (((size_t)((b<<3) + h)*2048 + s0) << 7);   // *128
#pragma unroll
    for (int j = 0; j < 8; ++j) {
      int off = wv*8192 + j*1024 + lane*16;   // byte offset in 32KB image (1KB/instr)
      int row = off >> 8;                     // s-local
      int col = (off >> 1) & 127;             // dh u16 index
      *(uint4*)&gout[(size_t)row*128 + col] = *(const uint4*)&Cs[row*136 + col];
    }
  } else {
#pragma unroll
    for (int ks=0; ks<4; ++ks) {
      v8s af[4], bf[4];
#pragma unroll
      for (int mi=0; mi<4; ++mi) af[mi] = *(const v8s*)&As[ks*4096 + (wm*64+mi*16+l16)*32 + quad*8];
#pragma unroll
      for (int ni=0; ni<4; ++ni) bf[ni] = *(const v8s*)&Ws[ks*4096 + (wn*64+ni*16+l16)*32 + quad*8];
#pragma unroll
      for (int mi=0; mi<4; ++mi)
#pragma unroll
        for (int ni=0; ni<4; ++ni)
          acc[mi][ni] = MFMA16(af[mi], bf[ni], acc[mi][ni]);
    }
    __syncthreads();               // all waves done reading As/Ws
    u16* Cs = smem;                // Cs[n][136]
#pragma unroll
    for (int ni=0; ni<4; ++ni) {
      int nl = wn*64 + ni*16 + l16;
      float bv = bias[n0 + nl];
#pragma unroll
      for (int mi=0; mi<4; ++mi) {
        int ml = wm*64 + mi*16 + quad*4;
        uint2 pk;
        pk.x = pk2(acc[mi][ni][0] + bv, acc[mi][ni][1] + bv);
        pk.y = pk2(acc[mi][ni][2] + bv, acc[mi][ni][3] + bv);
        *(uint2*)&Cs[nl*136 + ml] = pk;
      }
    }
    __syncthreads();
    const int nl = tid >> 1;                 // 0..127
    const int mb = (tid & 1) * 64;           // 0 or 64
    const int h = (n0 + nl) >> 7, dh = (n0 + nl) & 127;
    const int b = m0 >> 11, s0 = m0 & 2047;
    size_t gbase = (((size_t)((b<<3) + h)*128 + dh)*2048) + s0 + mb;
    size_t lbase = (size_t)nl*136 + mb;
#pragma unroll
    for (int j = 0; j < 8; ++j)
      *(uint4*)&out[gbase + j*8] = *(const uint4*)&Cs[lbase + j*8];
  }
}

// ---------------------------------------------------------------------------
// Kernel 2: flash attention — reverted to the R1-measured kernel (83.0 µs):
// R15 structure + chunk-XOR swizzled Ks/Vs + T5 setprio + T12 permlane.
// R4/R6 occupancy experiments (more blocks / more waves per SIMD) both
// regressed or were neutral; this config is the best measured.
// ---------------------------------------------------------------------------
__global__ __launch_bounds__(256, 2) void attn(
    const u16* __restrict__ Qp, const u16* __restrict__ Kp,
    const u16* __restrict__ Vt, u16* __restrict__ O)
{
  __shared__ u16 smem[32768];   // 64KB: Ks0@0, Ks1@8192, Vs0@16384, Vs1@24576

  const int tid = threadIdx.x, wv = tid>>6, lane = tid&63;
  const int l32 = lane&31, h = lane>>5;

  // bits [2:0]=xcd, [6:3]=qi, [8:7]=bh-hi: all 16 q-tiles of a bh on one XCD
  const int n  = blockIdx.x;
  const int bh = (n&7)*4 + (n>>7);
  const int q0 = ((n>>3)&15) * 128;

  const u16* Qb = Qp + (size_t)bh*262144 + (size_t)q0*128;
  const u16* Kb = Kp + (size_t)bh*262144;
  const u16* Vb = Vt + (size_t)bh*262144;

  // stage Q tile (128x128, 32KB) through smem, extract B-frags (one-time)
  for (int r = 0; r < 8; ++r) {
    int idx = r*256 + tid;
    int kd = idx>>8, q = (idx>>1)&127, hh = idx&1;
    gl16(Qb + q*128 + kd*16 + hh*8, &smem[idx*8]);
  }
  __syncthreads();
  const int qrow = wv*32 + l32;
  v8s qf[8];
#pragma unroll
  for (int kd = 0; kd < 8; ++kd)
    qf[kd] = *(const v8s*)&smem[kd*2048 + qrow*16 + h*8];
  __syncthreads();   // Q consumed; K/V buffers free

  // hoisted staging offsets with chunk-XOR swizzle (loop-invariant):
  // Ks slot idx -> key=idx>>4, pc=idx&15, src chunk = pc^(key&15)
  // Vs slot idx -> d=idx>>3,  pc=idx&7,  src chunk = pc^(d&7)
  int gK[4], gV[4], lK[4], lV[4];
#pragma unroll
  for (int r = 0; r < 4; ++r) {
    int idx = r*256 + tid;
    lK[r] = idx*8;  lV[r] = 16384 + idx*8;
    int key = idx>>4, pcK = idx&15;
    gK[r] = key*128 + ((pcK ^ (key&15)))*8;
    int d = idx>>3, pcV = idx&7;
    gV[r] = d*2048 + ((pcV ^ (d&7)))*8;
  }
  // per-lane fragment-read chunk offsets (u16 units)
  int kfo[8], vfo[4];
#pragma unroll
  for (int kd = 0; kd < 8; ++kd) kfo[kd] = ((kd*2 + h) ^ (l32 & 15)) * 8;
#pragma unroll
  for (int kt = 0; kt < 4; ++kt) vfo[kt] = ((kt*2 + h) ^ (l32 & 7)) * 8;

  v8s onesf;
#pragma unroll
  for (int j = 0; j < 8; ++j) onesf[j] = (short)0x3F80;  // bf16 1.0

  v16f oacc[4], lacc;
#pragma unroll
  for (int nt = 0; nt < 4; ++nt)
#pragma unroll
    for (int j = 0; j < 16; ++j) oacc[nt][j] = 0.f;
#pragma unroll
  for (int j = 0; j < 16; ++j) lacc[j] = 0.f;

  // stage tile 0 into buffer 0
#pragma unroll
  for (int r = 0; r < 4; ++r) gl16(Kb + gK[r], &smem[lK[r]]);
#pragma unroll
  for (int r = 0; r < 4; ++r) gl16(Vb + gV[r], &smem[lV[r]]);

  for (int it = 0; it < 32; ++it) {
    const int cur = it & 1;
    const int ko = cur*8192;            // current Ks base (u16 offset)
    const int vo = cur*8192;            // added to the 16384 Vs base
    __syncthreads();   // drains stage(it) + all waves done with buffer cur

    if (it + 1 < 32) { // prefetch tile it+1 into the other buffer
      const u16* Kt  = Kb + (it+1)*8192;
      const u16* Vtt = Vb + (it+1)*64;
      const int po = (cur^1)*8192;
#pragma unroll
      for (int r = 0; r < 4; ++r) gl16(Kt  + gK[r], &smem[po + lK[r]]);
#pragma unroll
      for (int r = 0; r < 4; ++r) gl16(Vtt + gV[r], &smem[po + lV[r] - 16384 + 16384]);
    }

    // S^T (64 keys x 32 q per wave) = K * Q^T   (Q pre-scaled by C2)
    v16f sa[2];
#pragma unroll
    for (int m = 0; m < 2; ++m)
#pragma unroll
      for (int j = 0; j < 16; ++j) sa[m][j] = 0.f;
    __builtin_amdgcn_s_setprio(1);      // T5: keep matrix pipe fed vs other block
#pragma unroll
    for (int kd = 0; kd < 8; ++kd) {
#pragma unroll
      for (int m = 0; m < 2; ++m) {
        v8s kf = *(const v8s*)&smem[ko + (m*32 + l32)*128 + kfo[kd]];
        sa[m] = MFMA32(kf, qf[kd], sa[m]);
      }
    }
    __builtin_amdgcn_s_setprio(0);

    // P = exp2(sa) packed to bf16 pairs (CB shift cancels in O/l).
    // Own keys (q=qrow): key = m*32 + g*8 + 4h + {0..3}  (regs 4g..4g+3)
    u32 P32[2][4][2];
#pragma unroll
    for (int m = 0; m < 2; ++m)
#pragma unroll
      for (int g = 0; g < 4; ++g) {
        P32[m][g][0] = pk2(__builtin_amdgcn_exp2f(sa[m][g*4+0]),
                           __builtin_amdgcn_exp2f(sa[m][g*4+1]));
        P32[m][g][1] = pk2(__builtin_amdgcn_exp2f(sa[m][g*4+2]),
                           __builtin_amdgcn_exp2f(sa[m][g*4+3]));
      }

    // Build PV A-frags in regs via lane^32 pair exchange.
    // T12: one permlane32_swap fills two output words.
    v8s pf[4];
#pragma unroll
    for (int kt = 0; kt < 4; ++kt) {
      const int m = kt >> 1, e = (kt & 1) * 2, o = e + 1;
      union { u32 u[4]; v8s s; } f;
#if __has_builtin(__builtin_amdgcn_permlane32_swap)
      v2i r0 = __builtin_amdgcn_permlane32_swap((int)P32[m][e][0], (int)P32[m][o][0], false, false);
      v2i r1 = __builtin_amdgcn_permlane32_swap((int)P32[m][e][1], (int)P32[m][o][1], false, false);
      f.u[0] = (u32)r0[0]; f.u[1] = (u32)r1[0];
      f.u[2] = (u32)r0[1]; f.u[3] = (u32)r1[1];
#else
      u32 a0 = P32[m][e][0], b0 = P32[m][o][0];
      u32 a1 = P32[m][e][1], b1 = P32[m][o][1];
      asm("v_permlane32_swap_b32 %0, %1" : "+v"(a0), "+v"(b0));
      asm("v_permlane32_swap_b32 %0, %1" : "+v"(a1), "+v"(b1));
      f.u[0] = a0; f.u[1] = a1; f.u[2] = b0; f.u[3] = b1;
#endif
      pf[kt] = f.s;
    }

    // O(32q x 128d) += P(32q x 64k) @ V(64k x 128d);  l += P @ ones
    __builtin_amdgcn_s_setprio(1);
#pragma unroll
    for (int kt = 0; kt < 4; ++kt) {
      lacc = MFMA32(pf[kt], onesf, lacc);
#pragma unroll
      for (int nt = 0; nt < 4; ++nt) {
        v8s vf = *(const v8s*)&smem[16384 + vo + (nt*32 + l32)*64 + vfo[kt]];
        oacc[nt] = MFMA32(pf[kt], vf, oacc[nt]);
      }
    }
    __builtin_amdgcn_s_setprio(0);
  }

  const int b = bh >> 3, hd = bh & 7;
#pragma unroll
  for (int reg = 0; reg < 16; ++reg) {
    int q = q0 + wv*32 + (reg&3) + 8*(reg>>2) + 4*h;
    float inv = 1.0f / lacc[reg];
    size_t base = ((size_t)(b*2048 + q))*1024 + hd*128;
#pragma unroll
    for (int nt = 0; nt < 4; ++nt)
      O[base + nt*32 + l32] = f2b(oacc[nt][reg] * inv);
  }
}

// ---------------------------------------------------------------------------
// Kernel 3: output projection (R16 double-buffered version, unchanged).
// ---------------------------------------------------------------------------
__global__ __launch_bounds__(256) void outproj(
    const u16* __restrict__ A, const float* __restrict__ Ww,
    const float* __restrict__ Wb, float* __restrict__ out)
{
  __shared__ u16 As[2][2048];  // [buf][2 kt][32 m][32 k]
  __shared__ u16 Ws[2][8192];  // [buf][2 kt][128 n][32 k]

  const int tid = threadIdx.x, wv = tid>>6, lane = tid&63;
  const int quad = lane>>4, l16 = lane&15;
  const int r4 = lane>>2, c4 = lane&3;
  const int m0 = blockIdx.x*32;

  v4f acc[2][2];   // [mi][nj], nt = wv*2 + nj
#pragma unroll
  for (int i=0;i<2;i++)
#pragma unroll
    for (int j=0;j<2;j++) acc[i][j] = (v4f){0.f,0.f,0.f,0.f};

  // stage chunk kb into buffer buf
  auto stage = [&](int kb, int buf) {
    {  // A tile: 4 regions, one per wave (bf16 internal -> gl16)
      int kt = wv >> 1, rg = wv & 1;
      int row = rg*16 + r4;
      gl16(A + (size_t)(m0+row)*1024 + kb + kt*32 + c4*8, &As[buf][kt*1024 + rg*512 + lane*8]);
    }
    for (int idx = wv; idx < 16; idx += 4) {   // W tile: fp32 -> bf16 staging
      int kt = idx >> 3, rg = idx & 7;
      int row = rg*16 + r4;
      stage8f(Ww + (size_t)row*1024 + kb + kt*32 + c4*8, &Ws[buf][kt*4096 + rg*512 + lane*8]);
    }
  };

  stage(0, 0);
  for (int kb = 0; kb < 1024; kb += 64) {
    const int cur = (kb >> 6) & 1;
    __syncthreads();   // drains stage(kb) + all waves done reading buf cur^1
    if (kb + 64 < 1024) stage(kb + 64, cur ^ 1);
#pragma unroll
    for (int ks = 0; ks < 2; ++ks) {
      v8s af0 = *(const v8s*)&As[cur][ks*1024 + (l16)*32 + quad*8];
      v8s af1 = *(const v8s*)&As[cur][ks*1024 + (16 + l16)*32 + quad*8];
#pragma unroll
      for (int nj = 0; nj < 2; ++nj) {
        v8s bf = *(const v8s*)&Ws[cur][ks*4096 + ((wv*2+nj)*16 + l16)*32 + quad*8];
        acc[0][nj] = MFMA16(af0, bf, acc[0][nj]);
        acc[1][nj] = MFMA16(af1, bf, acc[1][nj]);
      }
    }
  }

#pragma unroll
  for (int nj = 0; nj < 2; ++nj) {
    int col = (wv*2+nj)*16 + l16;
    float bv = Wb[col];
#pragma unroll
    for (int mi = 0; mi < 2; ++mi) {
#pragma unroll
      for (int r = 0; r < 4; ++r) {
        int row = m0 + mi*16 + quad*4 + r;
        out[(size_t)row*128 + col] = acc[mi][nj][r] + bv;
      }
    }
  }
}

// ---------------------------------------------------------------------------
extern "C" void kernel_launch(void* const* d_in, const int* in_sizes, int n_in,
                              void* d_out, int out_size, void* d_ws, size_t ws_size,
                              hipStream_t stream) {
  const float* Q   = (const float*)d_in[0];
  const float* K   = (const float*)d_in[1];
  const float* V   = (const float*)d_in[2];
  const float* WQw = (const float*)d_in[3];
  const float* WQb = (const float*)d_in[4];
  const float* WKw = (const float*)d_in[5];
  const float* WKb = (const float*)d_in[6];
  const float* WVw = (const float*)d_in[7];
  const float* WVb = (const float*)d_in[8];
  const float* Ww  = (const float*)d_in[9];
  const float* Wb  = (const float*)d_in[10];
  u16* ws = (u16*)d_ws;

  const size_t SZ = (size_t)4*8*2048*128;    // 8,388,608 elems per tensor
  u16* Qp = ws;
  u16* Kp = Qp + SZ;
  u16* Vt = Kp + SZ;
  u16* Ow = Vt + SZ;

  hipLaunchKernelGGL(proj_qkv, dim3(64,8,3), dim3(256), 0, stream,
                     Q,K,V,WQw,WQb,WKw,WKb,WVw,WVb,Qp,Kp,Vt);
  hipLaunchKernelGGL(attn, dim3(512), dim3(256), 0, stream, Qp,Kp,Vt,Ow);
  hipLaunchKernelGGL(outproj, dim3(256), dim3(256), 0, stream, Ow, Ww, Wb, (float*)d_out);
}

// Round 10
// 192.723 us; speedup vs baseline: 1.7273x; 1.0973x over previous
//
#include <hip/hip_runtime.h>
#include <hip/hip_bf16.h>

typedef unsigned short u16;
typedef unsigned int   u32;
typedef short v8s __attribute__((ext_vector_type(8)));
typedef float v4f __attribute__((ext_vector_type(4)));
typedef float v16f __attribute__((ext_vector_type(16)));
typedef int   v2i __attribute__((ext_vector_type(2)));

#define MFMA16(a,b,c) __builtin_amdgcn_mfma_f32_16x16x32_bf16(a,b,c,0,0,0)
#define MFMA32(a,b,c) __builtin_amdgcn_mfma_f32_32x32x16_bf16(a,b,c,0,0,0)

// Harness I/O dtype is FP32 (confirmed R11-R13 bisect). Internals bf16.
// Softmax scale C2 folded into Qp at proj; CB shift cancels in O/l.

__device__ __forceinline__ u16 f2b(float f){ u32 i; __builtin_memcpy(&i,&f,4); u32 r = (i + 0x7FFFu + ((i>>16)&1u))>>16; return (u16)r; }
__device__ __forceinline__ u32 pk2(float a, float b){
  __hip_bfloat162 h = __float22bfloat162_rn(make_float2(a,b));
  u32 r; __builtin_memcpy(&r,&h,4); return r;
}

// async global->LDS DMA, 16B per lane (bf16 sources only).
__device__ __forceinline__ void gl16(const void* g, void* l){
  __builtin_amdgcn_global_load_lds((const __attribute__((address_space(1))) u32*)g,
                                   (__attribute__((address_space(3))) u32*)l, 16, 0, 0);
}

// fp32 staging: 8 f32 -> 8 bf16 into LDS via packed v_cvt_pk_bf16_f32
__device__ __forceinline__ void stage8f(const float* g, u16* l){
  float4 a = *(const float4*)g, b = *(const float4*)(g+4);
  uint4 q;
  q.x = pk2(a.x, a.y); q.y = pk2(a.z, a.w);
  q.z = pk2(b.x, b.y); q.w = pk2(b.z, b.w);
  *(uint4*)l = q;
}

// ---------------------------------------------------------------------------
// Kernel 1: fused QKV projection (R8-measured version, unchanged this round).
// z=0: Qp[B,H,S,D] (PRE-SCALED by C2), z=1: Kp, z=2: Vt[B,H,D,S] transpose.
// ---------------------------------------------------------------------------
__global__ __launch_bounds__(256) void proj_qkv(
    const float* __restrict__ Qx, const float* __restrict__ Kx, const float* __restrict__ Vx,
    const float* __restrict__ WQw, const float* __restrict__ WQb,
    const float* __restrict__ WKw, const float* __restrict__ WKb,
    const float* __restrict__ WVw, const float* __restrict__ WVb,
    u16* __restrict__ Qp, u16* __restrict__ Kp, u16* __restrict__ Vt)
{
  __shared__ u16 smem[32768];          // As(16384) + Ws(16384); reused as Cs
  u16* As = smem;
  u16* Ws = smem + 16384;

  const int z = blockIdx.z;
  const float* X    = (z==0) ? Qx  : (z==1 ? Kx  : Vx);
  const float* W    = (z==0) ? WQw : (z==1 ? WKw : WVw);
  const float* bias = (z==0) ? WQb : (z==1 ? WKb : WVb);
  u16* out          = (z==0) ? Qp  : (z==1 ? Kp  : Vt);
  const float qs    = (z==0) ? 0.12751743076f : 1.0f;   // C2 fold into Q

  const int tid = threadIdx.x, wv = tid>>6, lane = tid&63;
  const int quad = lane>>4, l16 = lane&15;
  const int r4 = lane>>2, c4 = lane&3;
  const int m0 = blockIdx.x*128, n0 = blockIdx.y*128;

  for (int idx = wv; idx < 32; idx += 4) {
    int kt = idx >> 3, rg = idx & 7;
    int row = rg*16 + r4;
    stage8f(X + (size_t)(m0+row)*128 + kt*32 + c4*8, &As[kt*4096 + rg*512 + lane*8]);
    stage8f(W + (size_t)(n0+row)*128 + kt*32 + c4*8, &Ws[kt*4096 + rg*512 + lane*8]);
  }
  __syncthreads();

  const int wm = wv & 1, wn = wv >> 1;
  v4f acc[4][4];
#pragma unroll
  for (int i=0;i<4;i++)
#pragma unroll
    for (int j=0;j<4;j++) acc[i][j] = (v4f){0.f,0.f,0.f,0.f};

  if (z < 2) {
#pragma unroll
    for (int ks=0; ks<4; ++ks) {
      v8s af[4], bf[4];
#pragma unroll
      for (int mi=0; mi<4; ++mi) af[mi] = *(const v8s*)&As[ks*4096 + (wm*64+mi*16+l16)*32 + quad*8];
#pragma unroll
      for (int ni=0; ni<4; ++ni) bf[ni] = *(const v8s*)&Ws[ks*4096 + (wn*64+ni*16+l16)*32 + quad*8];
#pragma unroll
      for (int mi=0; mi<4; ++mi)
#pragma unroll
        for (int ni=0; ni<4; ++ni)
          acc[mi][ni] = MFMA16(bf[ni], af[mi], acc[mi][ni]);   // A=W, B=X
    }
    __syncthreads();               // As/Ws consumed; smem free for Cs
    u16* Cs = smem;                // Cs[m-local 128][136]
#pragma unroll
    for (int ni=0; ni<4; ++ni) {
      int nl = wn*64 + ni*16 + quad*4;        // d-local, 4 consecutive (r)
      int nb = n0 + nl;
      float bv0 = bias[nb+0]*qs;
      float bv1 = bias[nb+1]*qs;
      float bv2 = bias[nb+2]*qs;
      float bv3 = bias[nb+3]*qs;
#pragma unroll
      for (int mi=0; mi<4; ++mi) {
        int ml = wm*64 + mi*16 + l16;         // m-local
        uint2 pk;
        pk.x = pk2(fmaf(acc[mi][ni][0], qs, bv0), fmaf(acc[mi][ni][1], qs, bv1));
        pk.y = pk2(fmaf(acc[mi][ni][2], qs, bv2), fmaf(acc[mi][ni][3], qs, bv3));
        *(uint2*)&Cs[ml*136 + nl] = pk;
      }
    }
    __syncthreads();
    // coalesced writeout: 32KB tile image is contiguous in global
    const int h = n0 >> 7;
    const int b = m0 >> 11, s0 = m0 & 2047;
    u16* gout = out + (((size_t)((b<<3) + h)*2048 + s0) << 7);   // *128
#pragma unroll
    for (int j = 0; j < 8; ++j) {
      int off = wv*8192 + j*1024 + lane*16;   // byte offset in 32KB image (1KB/instr)
      int row = off >> 8;                     // s-local
      int col = (off >> 1) & 127;             // dh u16 index
      *(uint4*)&gout[(size_t)row*128 + col] = *(const uint4*)&Cs[row*136 + col];
    }
  } else {
#pragma unroll
    for (int ks=0; ks<4; ++ks) {
      v8s af[4], bf[4];
#pragma unroll
      for (int mi=0; mi<4; ++mi) af[mi] = *(const v8s*)&As[ks*4096 + (wm*64+mi*16+l16)*32 + quad*8];
#pragma unroll
      for (int ni=0; ni<4; ++ni) bf[ni] = *(const v8s*)&Ws[ks*4096 + (wn*64+ni*16+l16)*32 + quad*8];
#pragma unroll
      for (int mi=0; mi<4; ++mi)
#pragma unroll
        for (int ni=0; ni<4; ++ni)
          acc[mi][ni] = MFMA16(af[mi], bf[ni], acc[mi][ni]);
    }
    __syncthreads();               // all waves done reading As/Ws
    u16* Cs = smem;                // Cs[n][136]
#pragma unroll
    for (int ni=0; ni<4; ++ni) {
      int nl = wn*64 + ni*16 + l16;
      float bv = bias[n0 + nl];
#pragma unroll
      for (int mi=0; mi<4; ++mi) {
        int ml = wm*64 + mi*16 + quad*4;
        uint2 pk;
        pk.x = pk2(acc[mi][ni][0] + bv, acc[mi][ni][1] + bv);
        pk.y = pk2(acc[mi][ni][2] + bv, acc[mi][ni][3] + bv);
        *(uint2*)&Cs[nl*136 + ml] = pk;
      }
    }
    __syncthreads();
    const int nl = tid >> 1;                 // 0..127
    const int mb = (tid & 1) * 64;           // 0 or 64
    const int h = (n0 + nl) >> 7, dh = (n0 + nl) & 127;
    const int b = m0 >> 11, s0 = m0 & 2047;
    size_t gbase = (((size_t)((b<<3) + h)*128 + dh)*2048) + s0 + mb;
    size_t lbase = (size_t)nl*136 + mb;
#pragma unroll
    for (int j = 0; j < 8; ++j)
      *(uint4*)&out[gbase + j*8] = *(const uint4*)&Cs[lbase + j*8];
  }
}

// ---------------------------------------------------------------------------
// Kernel 2: flash attention — R1-measured kernel, unchanged (83-85 µs).
// ---------------------------------------------------------------------------
__global__ __launch_bounds__(256, 2) void attn(
    const u16* __restrict__ Qp, const u16* __restrict__ Kp,
    const u16* __restrict__ Vt, u16* __restrict__ O)
{
  __shared__ u16 smem[32768];   // 64KB: Ks0@0, Ks1@8192, Vs0@16384, Vs1@24576

  const int tid = threadIdx.x, wv = tid>>6, lane = tid&63;
  const int l32 = lane&31, h = lane>>5;

  const int n  = blockIdx.x;
  const int bh = (n&7)*4 + (n>>7);
  const int q0 = ((n>>3)&15) * 128;

  const u16* Qb = Qp + (size_t)bh*262144 + (size_t)q0*128;
  const u16* Kb = Kp + (size_t)bh*262144;
  const u16* Vb = Vt + (size_t)bh*262144;

  for (int r = 0; r < 8; ++r) {
    int idx = r*256 + tid;
    int kd = idx>>8, q = (idx>>1)&127, hh = idx&1;
    gl16(Qb + q*128 + kd*16 + hh*8, &smem[idx*8]);
  }
  __syncthreads();
  const int qrow = wv*32 + l32;
  v8s qf[8];
#pragma unroll
  for (int kd = 0; kd < 8; ++kd)
    qf[kd] = *(const v8s*)&smem[kd*2048 + qrow*16 + h*8];
  __syncthreads();   // Q consumed; K/V buffers free

  int gK[4], gV[4], lK[4], lV[4];
#pragma unroll
  for (int r = 0; r < 4; ++r) {
    int idx = r*256 + tid;
    lK[r] = idx*8;  lV[r] = 16384 + idx*8;
    int key = idx>>4, pcK = idx&15;
    gK[r] = key*128 + ((pcK ^ (key&15)))*8;
    int d = idx>>3, pcV = idx&7;
    gV[r] = d*2048 + ((pcV ^ (d&7)))*8;
  }
  int kfo[8], vfo[4];
#pragma unroll
  for (int kd = 0; kd < 8; ++kd) kfo[kd] = ((kd*2 + h) ^ (l32 & 15)) * 8;
#pragma unroll
  for (int kt = 0; kt < 4; ++kt) vfo[kt] = ((kt*2 + h) ^ (l32 & 7)) * 8;

  v8s onesf;
#pragma unroll
  for (int j = 0; j < 8; ++j) onesf[j] = (short)0x3F80;  // bf16 1.0

  v16f oacc[4], lacc;
#pragma unroll
  for (int nt = 0; nt < 4; ++nt)
#pragma unroll
    for (int j = 0; j < 16; ++j) oacc[nt][j] = 0.f;
#pragma unroll
  for (int j = 0; j < 16; ++j) lacc[j] = 0.f;

#pragma unroll
  for (int r = 0; r < 4; ++r) gl16(Kb + gK[r], &smem[lK[r]]);
#pragma unroll
  for (int r = 0; r < 4; ++r) gl16(Vb + gV[r], &smem[lV[r]]);

  for (int it = 0; it < 32; ++it) {
    const int cur = it & 1;
    const int ko = cur*8192;
    const int vo = cur*8192;
    __syncthreads();

    if (it + 1 < 32) {
      const u16* Kt  = Kb + (it+1)*8192;
      const u16* Vtt = Vb + (it+1)*64;
      const int po = (cur^1)*8192;
#pragma unroll
      for (int r = 0; r < 4; ++r) gl16(Kt  + gK[r], &smem[po + lK[r]]);
#pragma unroll
      for (int r = 0; r < 4; ++r) gl16(Vtt + gV[r], &smem[po + lV[r] - 16384 + 16384]);
    }

    v16f sa[2];
#pragma unroll
    for (int m = 0; m < 2; ++m)
#pragma unroll
      for (int j = 0; j < 16; ++j) sa[m][j] = 0.f;
    __builtin_amdgcn_s_setprio(1);
#pragma unroll
    for (int kd = 0; kd < 8; ++kd) {
#pragma unroll
      for (int m = 0; m < 2; ++m) {
        v8s kf = *(const v8s*)&smem[ko + (m*32 + l32)*128 + kfo[kd]];
        sa[m] = MFMA32(kf, qf[kd], sa[m]);
      }
    }
    __builtin_amdgcn_s_setprio(0);

    u32 P32[2][4][2];
#pragma unroll
    for (int m = 0; m < 2; ++m)
#pragma unroll
      for (int g = 0; g < 4; ++g) {
        P32[m][g][0] = pk2(__builtin_amdgcn_exp2f(sa[m][g*4+0]),
                           __builtin_amdgcn_exp2f(sa[m][g*4+1]));
        P32[m][g][1] = pk2(__builtin_amdgcn_exp2f(sa[m][g*4+2]),
                           __builtin_amdgcn_exp2f(sa[m][g*4+3]));
      }

    v8s pf[4];
#pragma unroll
    for (int kt = 0; kt < 4; ++kt) {
      const int m = kt >> 1, e = (kt & 1) * 2, o = e + 1;
      union { u32 u[4]; v8s s; } f;
#if __has_builtin(__builtin_amdgcn_permlane32_swap)
      v2i r0 = __builtin_amdgcn_permlane32_swap((int)P32[m][e][0], (int)P32[m][o][0], false, false);
      v2i r1 = __builtin_amdgcn_permlane32_swap((int)P32[m][e][1], (int)P32[m][o][1], false, false);
      f.u[0] = (u32)r0[0]; f.u[1] = (u32)r1[0];
      f.u[2] = (u32)r0[1]; f.u[3] = (u32)r1[1];
#else
      u32 a0 = P32[m][e][0], b0 = P32[m][o][0];
      u32 a1 = P32[m][e][1], b1 = P32[m][o][1];
      asm("v_permlane32_swap_b32 %0, %1" : "+v"(a0), "+v"(b0));
      asm("v_permlane32_swap_b32 %0, %1" : "+v"(a1), "+v"(b1));
      f.u[0] = a0; f.u[1] = a1; f.u[2] = b0; f.u[3] = b1;
#endif
      pf[kt] = f.s;
    }

    __builtin_amdgcn_s_setprio(1);
#pragma unroll
    for (int kt = 0; kt < 4; ++kt) {
      lacc = MFMA32(pf[kt], onesf, lacc);
#pragma unroll
      for (int nt = 0; nt < 4; ++nt) {
        v8s vf = *(const v8s*)&smem[16384 + vo + (nt*32 + l32)*64 + vfo[kt]];
        oacc[nt] = MFMA32(pf[kt], vf, oacc[nt]);
      }
    }
    __builtin_amdgcn_s_setprio(0);
  }

  const int b = bh >> 3, hd = bh & 7;
#pragma unroll
  for (int reg = 0; reg < 16; ++reg) {
    int q = q0 + wv*32 + (reg&3) + 8*(reg>>2) + 4*h;
    float inv = 1.0f / lacc[reg];
    size_t base = ((size_t)(b*2048 + q))*1024 + hd*128;
#pragma unroll
    for (int nt = 0; nt < 4; ++nt)
      O[base + nt*32 + l32] = f2b(oacc[nt][reg] * inv);
  }
}

// ---------------------------------------------------------------------------
// Kernel 3: output projection — R21 split-K x4. Old: grid 256 = 1 block/CU,
// 16 fully serial K-chunks, each barrier+load-latency gated -> suspected
// latency hog (designed as a measurement: only this kernel changes).
// Now: grid 1024 = (256 m-tiles) x (4 K-splits of 256), 4 blocks/CU
// (40KB LDS x 4 = 160KB), 4 chunks per block. Partials (f32) land in the
// dead Qp/Kp workspace region; outred sums 4 partials + bias -> out.
// ---------------------------------------------------------------------------
__global__ __launch_bounds__(256) void outproj(
    const u16* __restrict__ A, const float* __restrict__ Ww,
    float* __restrict__ P)    // partials [4][8192][128] f32
{
  __shared__ u16 As[2][2048];  // [buf][2 kt][32 m][32 k]
  __shared__ u16 Ws[2][8192];  // [buf][2 kt][128 n][32 k]

  const int tid = threadIdx.x, wv = tid>>6, lane = tid&63;
  const int quad = lane>>4, l16 = lane&15;
  const int r4 = lane>>2, c4 = lane&3;
  const int m0 = (blockIdx.x >> 2) * 32;
  const int k0 = (blockIdx.x & 3) * 256;

  v4f acc[2][2];   // [mi][nj], nt = wv*2 + nj
#pragma unroll
  for (int i=0;i<2;i++)
#pragma unroll
    for (int j=0;j<2;j++) acc[i][j] = (v4f){0.f,0.f,0.f,0.f};

  auto stage = [&](int kb, int buf) {
    {  // A tile: 4 regions, one per wave (bf16 internal -> gl16)
      int kt = wv >> 1, rg = wv & 1;
      int row = rg*16 + r4;
      gl16(A + (size_t)(m0+row)*1024 + k0 + kb + kt*32 + c4*8, &As[buf][kt*1024 + rg*512 + lane*8]);
    }
    for (int idx = wv; idx < 16; idx += 4) {   // W tile: fp32 -> bf16 staging
      int kt = idx >> 3, rg = idx & 7;
      int row = rg*16 + r4;
      stage8f(Ww + (size_t)row*1024 + k0 + kb + kt*32 + c4*8, &Ws[buf][kt*4096 + rg*512 + lane*8]);
    }
  };

  stage(0, 0);
  for (int kb = 0; kb < 256; kb += 64) {
    const int cur = (kb >> 6) & 1;
    __syncthreads();   // drains stage(kb) + all waves done reading buf cur^1
    if (kb + 64 < 256) stage(kb + 64, cur ^ 1);
#pragma unroll
    for (int ks = 0; ks < 2; ++ks) {
      v8s af0 = *(const v8s*)&As[cur][ks*1024 + (l16)*32 + quad*8];
      v8s af1 = *(const v8s*)&As[cur][ks*1024 + (16 + l16)*32 + quad*8];
#pragma unroll
      for (int nj = 0; nj < 2; ++nj) {
        v8s bf = *(const v8s*)&Ws[cur][ks*4096 + ((wv*2+nj)*16 + l16)*32 + quad*8];
        acc[0][nj] = MFMA16(af0, bf, acc[0][nj]);
        acc[1][nj] = MFMA16(af1, bf, acc[1][nj]);
      }
    }
  }

  float* out = P + (size_t)(blockIdx.x & 3) * 1048576;   // partial kz plane
#pragma unroll
  for (int nj = 0; nj < 2; ++nj) {
    int col = (wv*2+nj)*16 + l16;
#pragma unroll
    for (int mi = 0; mi < 2; ++mi) {
#pragma unroll
      for (int r = 0; r < 4; ++r) {
        int row = m0 + mi*16 + quad*4 + r;
        out[(size_t)row*128 + col] = acc[mi][nj][r];
      }
    }
  }
}

// reduce: out = P0+P1+P2+P3 + bias.  1024 blocks x 256 thr x 4 f32 = 1,048,576.
__global__ __launch_bounds__(256) void outred(
    const float* __restrict__ P, const float* __restrict__ Wb,
    float* __restrict__ out)
{
  int i0 = (blockIdx.x*256 + threadIdx.x)*4;
  float4 a = *(const float4*)&P[i0];
  float4 b = *(const float4*)&P[1048576 + i0];
  float4 c = *(const float4*)&P[2097152 + i0];
  float4 d = *(const float4*)&P[3145728 + i0];
  float4 bv = *(const float4*)&Wb[i0 & 127];
  float4 r;
  r.x = a.x + b.x + c.x + d.x + bv.x;
  r.y = a.y + b.y + c.y + d.y + bv.y;
  r.z = a.z + b.z + c.z + d.z + bv.z;
  r.w = a.w + b.w + c.w + d.w + bv.w;
  *(float4*)&out[i0] = r;
}

// ---------------------------------------------------------------------------
extern "C" void kernel_launch(void* const* d_in, const int* in_sizes, int n_in,
                              void* d_out, int out_size, void* d_ws, size_t ws_size,
                              hipStream_t stream) {
  const float* Q   = (const float*)d_in[0];
  const float* K   = (const float*)d_in[1];
  const float* V   = (const float*)d_in[2];
  const float* WQw = (const float*)d_in[3];
  const float* WQb = (const float*)d_in[4];
  const float* WKw = (const float*)d_in[5];
  const float* WKb = (const float*)d_in[6];
  const float* WVw = (const float*)d_in[7];
  const float* WVb = (const float*)d_in[8];
  const float* Ww  = (const float*)d_in[9];
  const float* Wb  = (const float*)d_in[10];
  u16* ws = (u16*)d_ws;

  const size_t SZ = (size_t)4*8*2048*128;    // 8,388,608 elems per tensor
  u16* Qp = ws;
  u16* Kp = Qp + SZ;
  u16* Vt = Kp + SZ;
  u16* Ow = Vt + SZ;
  float* Pp = (float*)ws;   // partials overlay Qp+Kp (dead after attn): 16.8MB < 32MB

  hipLaunchKernelGGL(proj_qkv, dim3(64,8,3), dim3(256), 0, stream,
                     Q,K,V,WQw,WQb,WKw,WKb,WVw,WVb,Qp,Kp,Vt);
  hipLaunchKernelGGL(attn, dim3(512), dim3(256), 0, stream, Qp,Kp,Vt,Ow);
  hipLaunchKernelGGL(outproj, dim3(1024), dim3(256), 0, stream, Ow, Ww, Pp);
  hipLaunchKernelGGL(outred, dim3(1024), dim3(256), 0, stream, Pp, Wb, (float*)d_out);
}

// Round 13
// 189.517 us; speedup vs baseline: 1.7565x; 1.0169x over previous
//
#include <hip/hip_runtime.h>
#include <hip/hip_bf16.h>

typedef unsigned short u16;
typedef unsigned int   u32;
typedef short v8s __attribute__((ext_vector_type(8)));
typedef float v4f __attribute__((ext_vector_type(4)));
typedef float v16f __attribute__((ext_vector_type(16)));
typedef int   v2i __attribute__((ext_vector_type(2)));

#define MFMA16(a,b,c) __builtin_amdgcn_mfma_f32_16x16x32_bf16(a,b,c,0,0,0)
#define MFMA32(a,b,c) __builtin_amdgcn_mfma_f32_32x32x16_bf16(a,b,c,0,0,0)

// Harness I/O dtype is FP32. Internals bf16.
// Softmax scale C2 folded into Qp at proj; CB shift cancels in O/l.

__device__ __forceinline__ u16 f2b(float f){ u32 i; __builtin_memcpy(&i,&f,4); u32 r = (i + 0x7FFFu + ((i>>16)&1u))>>16; return (u16)r; }
__device__ __forceinline__ u32 pk2(float a, float b){
  __hip_bfloat162 h = __float22bfloat162_rn(make_float2(a,b));
  u32 r; __builtin_memcpy(&r,&h,4); return r;
}

// async global->LDS DMA, 16B per lane (bf16 sources only).
__device__ __forceinline__ void gl16(const void* g, void* l){
  __builtin_amdgcn_global_load_lds((const __attribute__((address_space(1))) u32*)g,
                                   (__attribute__((address_space(3))) u32*)l, 16, 0, 0);
}

// fp32: 8 f32 -> 8 bf16 via packed v_cvt_pk_bf16_f32 (dst may be global or LDS)
__device__ __forceinline__ void stage8f(const float* g, u16* l){
  float4 a = *(const float4*)g, b = *(const float4*)(g+4);
  uint4 q;
  q.x = pk2(a.x, a.y); q.y = pk2(a.z, a.w);
  q.z = pk2(b.x, b.y); q.w = pk2(b.z, b.w);
  *(uint4*)l = q;
}

// ---------------------------------------------------------------------------
// Kernel 0 (R22): one-time fp32->bf16 convert of proj inputs.
// Rationale: old proj re-converted X 8x and W 64x per matrix through
// stage8f (2 loads + 4 cvt + 1 LDS-write per 16B = Common-mistake #1).
// Convert ONCE (14MB read + 7MB write ~ 4us), then proj stages pure-bf16
// via global_load_lds DMA. Outputs overlay the Ow region (dead until attn).
// ---------------------------------------------------------------------------
__global__ __launch_bounds__(256) void cvt(
    const float* __restrict__ Qx, const float* __restrict__ Kx, const float* __restrict__ Vx,
    const float* __restrict__ WQw, const float* __restrict__ WKw, const float* __restrict__ WVw,
    u16* __restrict__ Xq, u16* __restrict__ Xk, u16* __restrict__ Xv,
    u16* __restrict__ Wq, u16* __restrict__ Wk, u16* __restrict__ Wv)
{
  const int seg = blockIdx.y;
  const float* src = seg==0?Qx : seg==1?Kx : seg==2?Vx : seg==3?WQw : seg==4?WKw : WVw;
  u16* dst        = seg==0?Xq : seg==1?Xk : seg==2?Xv : seg==3?Wq  : seg==4?Wk  : Wv;
  const int n = (seg < 3) ? 1048576 : 131072;
  int base = (blockIdx.x*256 + threadIdx.x)*8;
  if (base >= n) return;
  stage8f(src + base, dst + base);
}

// ---------------------------------------------------------------------------
// Kernel 1: fused QKV projection — R22: staging switched from fp32 stage8f
// to bf16 gl16 DMA (inputs pre-converted by cvt). LDS layouts, fragment
// reads, MFMA order, epilogues, and index algebra are byte-identical to the
// R8/R10-measured kernel. gl16 dest = wave-uniform base + lane*16B (HW
// constraint satisfied: &As[kt*4096+rg*512+lane*8]); global src per-lane.
// z=0: Qp[B,H,S,D] (PRE-SCALED by C2), z=1: Kp, z=2: Vt[B,H,D,S] transpose.
// ---------------------------------------------------------------------------
__global__ __launch_bounds__(256) void proj_qkv(
    const u16* __restrict__ Xq, const u16* __restrict__ Xk, const u16* __restrict__ Xv,
    const u16* __restrict__ Wq, const u16* __restrict__ Wk, const u16* __restrict__ Wv,
    const float* __restrict__ WQb, const float* __restrict__ WKb, const float* __restrict__ WVb,
    u16* __restrict__ Qp, u16* __restrict__ Kp, u16* __restrict__ Vt)
{
  __shared__ u16 smem[32768];          // As(16384) + Ws(16384); reused as Cs
  u16* As = smem;
  u16* Ws = smem + 16384;

  const int z = blockIdx.z;
  const u16* X      = (z==0) ? Xq  : (z==1 ? Xk  : Xv);
  const u16* W      = (z==0) ? Wq  : (z==1 ? Wk  : Wv);
  const float* bias = (z==0) ? WQb : (z==1 ? WKb : WVb);
  u16* out          = (z==0) ? Qp  : (z==1 ? Kp  : Vt);
  const float qs    = (z==0) ? 0.12751743076f : 1.0f;   // C2 fold into Q

  const int tid = threadIdx.x, wv = tid>>6, lane = tid&63;
  const int quad = lane>>4, l16 = lane&15;
  const int r4 = lane>>2, c4 = lane&3;
  const int m0 = blockIdx.x*128, n0 = blockIdx.y*128;

  for (int idx = wv; idx < 32; idx += 4) {
    int kt = idx >> 3, rg = idx & 7;
    int row = rg*16 + r4;
    gl16(X + (size_t)(m0+row)*128 + kt*32 + c4*8, &As[kt*4096 + rg*512 + lane*8]);
    gl16(W + (size_t)(n0+row)*128 + kt*32 + c4*8, &Ws[kt*4096 + rg*512 + lane*8]);
  }
  __syncthreads();

  const int wm = wv & 1, wn = wv >> 1;
  v4f acc[4][4];
#pragma unroll
  for (int i=0;i<4;i++)
#pragma unroll
    for (int j=0;j<4;j++) acc[i][j] = (v4f){0.f,0.f,0.f,0.f};

  if (z < 2) {
#pragma unroll
    for (int ks=0; ks<4; ++ks) {
      v8s af[4], bf[4];
#pragma unroll
      for (int mi=0; mi<4; ++mi) af[mi] = *(const v8s*)&As[ks*4096 + (wm*64+mi*16+l16)*32 + quad*8];
#pragma unroll
      for (int ni=0; ni<4; ++ni) bf[ni] = *(const v8s*)&Ws[ks*4096 + (wn*64+ni*16+l16)*32 + quad*8];
#pragma unroll
      for (int mi=0; mi<4; ++mi)
#pragma unroll
        for (int ni=0; ni<4; ++ni)
          acc[mi][ni] = MFMA16(bf[ni], af[mi], acc[mi][ni]);   // A=W, B=X
    }
    __syncthreads();               // As/Ws consumed; smem free for Cs
    u16* Cs = smem;                // Cs[m-local 128][136]
#pragma unroll
    for (int ni=0; ni<4; ++ni) {
      int nl = wn*64 + ni*16 + quad*4;        // d-local, 4 consecutive (r)
      int nb = n0 + nl;
      float bv0 = bias[nb+0]*qs;
      float bv1 = bias[nb+1]*qs;
      float bv2 = bias[nb+2]*qs;
      float bv3 = bias[nb+3]*qs;
#pragma unroll
      for (int mi=0; mi<4; ++mi) {
        int ml = wm*64 + mi*16 + l16;         // m-local
        uint2 pk;
        pk.x = pk2(fmaf(acc[mi][ni][0], qs, bv0), fmaf(acc[mi][ni][1], qs, bv1));
        pk.y = pk2(fmaf(acc[mi][ni][2], qs, bv2), fmaf(acc[mi][ni][3], qs, bv3));
        *(uint2*)&Cs[ml*136 + nl] = pk;
      }
    }
    __syncthreads();
    // coalesced writeout: 32KB tile image is contiguous in global
    const int h = n0 >> 7;
    const int b = m0 >> 11, s0 = m0 & 2047;
    u16* gout = out + (((size_t)((b<<3) + h)*2048 + s0) << 7);   // *128
#pragma unroll
    for (int j = 0; j < 8; ++j) {
      int off = wv*8192 + j*1024 + lane*16;   // byte offset in 32KB image (1KB/instr)
      int row = off >> 8;                     // s-local
      int col = (off >> 1) & 127;             // dh u16 index
      *(uint4*)&gout[(size_t)row*128 + col] = *(const uint4*)&Cs[row*136 + col];
    }
  } else {
#pragma unroll
    for (int ks=0; ks<4; ++ks) {
      v8s af[4], bf[4];
#pragma unroll
      for (int mi=0; mi<4; ++mi) af[mi] = *(const v8s*)&As[ks*4096 + (wm*64+mi*16+l16)*32 + quad*8];
#pragma unroll
      for (int ni=0; ni<4; ++ni) bf[ni] = *(const v8s*)&Ws[ks*4096 + (wn*64+ni*16+l16)*32 + quad*8];
#pragma unroll
      for (int mi=0; mi<4; ++mi)
#pragma unroll
        for (int ni=0; ni<4; ++ni)
          acc[mi][ni] = MFMA16(af[mi], bf[ni], acc[mi][ni]);
    }
    __syncthreads();               // all waves done reading As/Ws
    u16* Cs = smem;                // Cs[n][136]
#pragma unroll
    for (int ni=0; ni<4; ++ni) {
      int nl = wn*64 + ni*16 + l16;
      float bv = bias[n0 + nl];
#pragma unroll
      for (int mi=0; mi<4; ++mi) {
        int ml = wm*64 + mi*16 + quad*4;
        uint2 pk;
        pk.x = pk2(acc[mi][ni][0] + bv, acc[mi][ni][1] + bv);
        pk.y = pk2(acc[mi][ni][2] + bv, acc[mi][ni][3] + bv);
        *(uint2*)&Cs[nl*136 + ml] = pk;
      }
    }
    __syncthreads();
    const int nl = tid >> 1;                 // 0..127
    const int mb = (tid & 1) * 64;           // 0 or 64
    const int h = (n0 + nl) >> 7, dh = (n0 + nl) & 127;
    const int b = m0 >> 11, s0 = m0 & 2047;
    size_t gbase = (((size_t)((b<<3) + h)*128 + dh)*2048) + s0 + mb;
    size_t lbase = (size_t)nl*136 + mb;
#pragma unroll
    for (int j = 0; j < 8; ++j)
      *(uint4*)&out[gbase + j*8] = *(const uint4*)&Cs[lbase + j*8];
  }
}

// ---------------------------------------------------------------------------
// Kernel 2: flash attention — R1-measured kernel, unchanged (82-85 µs).
// ---------------------------------------------------------------------------
__global__ __launch_bounds__(256, 2) void attn(
    const u16* __restrict__ Qp, const u16* __restrict__ Kp,
    const u16* __restrict__ Vt, u16* __restrict__ O)
{
  __shared__ u16 smem[32768];   // 64KB: Ks0@0, Ks1@8192, Vs0@16384, Vs1@24576

  const int tid = threadIdx.x, wv = tid>>6, lane = tid&63;
  const int l32 = lane&31, h = lane>>5;

  const int n  = blockIdx.x;
  const int bh = (n&7)*4 + (n>>7);
  const int q0 = ((n>>3)&15) * 128;

  const u16* Qb = Qp + (size_t)bh*262144 + (size_t)q0*128;
  const u16* Kb = Kp + (size_t)bh*262144;
  const u16* Vb = Vt + (size_t)bh*262144;

  for (int r = 0; r < 8; ++r) {
    int idx = r*256 + tid;
    int kd = idx>>8, q = (idx>>1)&127, hh = idx&1;
    gl16(Qb + q*128 + kd*16 + hh*8, &smem[idx*8]);
  }
  __syncthreads();
  const int qrow = wv*32 + l32;
  v8s qf[8];
#pragma unroll
  for (int kd = 0; kd < 8; ++kd)
    qf[kd] = *(const v8s*)&smem[kd*2048 + qrow*16 + h*8];
  __syncthreads();   // Q consumed; K/V buffers free

  int gK[4], gV[4], lK[4], lV[4];
#pragma unroll
  for (int r = 0; r < 4; ++r) {
    int idx = r*256 + tid;
    lK[r] = idx*8;  lV[r] = 16384 + idx*8;
    int key = idx>>4, pcK = idx&15;
    gK[r] = key*128 + ((pcK ^ (key&15)))*8;
    int d = idx>>3, pcV = idx&7;
    gV[r] = d*2048 + ((pcV ^ (d&7)))*8;
  }
  int kfo[8], vfo[4];
#pragma unroll
  for (int kd = 0; kd < 8; ++kd) kfo[kd] = ((kd*2 + h) ^ (l32 & 15)) * 8;
#pragma unroll
  for (int kt = 0; kt < 4; ++kt) vfo[kt] = ((kt*2 + h) ^ (l32 & 7)) * 8;

  v8s onesf;
#pragma unroll
  for (int j = 0; j < 8; ++j) onesf[j] = (short)0x3F80;  // bf16 1.0

  v16f oacc[4], lacc;
#pragma unroll
  for (int nt = 0; nt < 4; ++nt)
#pragma unroll
    for (int j = 0; j < 16; ++j) oacc[nt][j] = 0.f;
#pragma unroll
  for (int j = 0; j < 16; ++j) lacc[j] = 0.f;

#pragma unroll
  for (int r = 0; r < 4; ++r) gl16(Kb + gK[r], &smem[lK[r]]);
#pragma unroll
  for (int r = 0; r < 4; ++r) gl16(Vb + gV[r], &smem[lV[r]]);

  for (int it = 0; it < 32; ++it) {
    const int cur = it & 1;
    const int ko = cur*8192;
    const int vo = cur*8192;
    __syncthreads();

    if (it + 1 < 32) {
      const u16* Kt  = Kb + (it+1)*8192;
      const u16* Vtt = Vb + (it+1)*64;
      const int po = (cur^1)*8192;
#pragma unroll
      for (int r = 0; r < 4; ++r) gl16(Kt  + gK[r], &smem[po + lK[r]]);
#pragma unroll
      for (int r = 0; r < 4; ++r) gl16(Vtt + gV[r], &smem[po + lV[r] - 16384 + 16384]);
    }

    v16f sa[2];
#pragma unroll
    for (int m = 0; m < 2; ++m)
#pragma unroll
      for (int j = 0; j < 16; ++j) sa[m][j] = 0.f;
    __builtin_amdgcn_s_setprio(1);
#pragma unroll
    for (int kd = 0; kd < 8; ++kd) {
#pragma unroll
      for (int m = 0; m < 2; ++m) {
        v8s kf = *(const v8s*)&smem[ko + (m*32 + l32)*128 + kfo[kd]];
        sa[m] = MFMA32(kf, qf[kd], sa[m]);
      }
    }
    __builtin_amdgcn_s_setprio(0);

    u32 P32[2][4][2];
#pragma unroll
    for (int m = 0; m < 2; ++m)
#pragma unroll
      for (int g = 0; g < 4; ++g) {
        P32[m][g][0] = pk2(__builtin_amdgcn_exp2f(sa[m][g*4+0]),
                           __builtin_amdgcn_exp2f(sa[m][g*4+1]));
        P32[m][g][1] = pk2(__builtin_amdgcn_exp2f(sa[m][g*4+2]),
                           __builtin_amdgcn_exp2f(sa[m][g*4+3]));
      }

    v8s pf[4];
#pragma unroll
    for (int kt = 0; kt < 4; ++kt) {
      const int m = kt >> 1, e = (kt & 1) * 2, o = e + 1;
      union { u32 u[4]; v8s s; } f;
#if __has_builtin(__builtin_amdgcn_permlane32_swap)
      v2i r0 = __builtin_amdgcn_permlane32_swap((int)P32[m][e][0], (int)P32[m][o][0], false, false);
      v2i r1 = __builtin_amdgcn_permlane32_swap((int)P32[m][e][1], (int)P32[m][o][1], false, false);
      f.u[0] = (u32)r0[0]; f.u[1] = (u32)r1[0];
      f.u[2] = (u32)r0[1]; f.u[3] = (u32)r1[1];
#else
      u32 a0 = P32[m][e][0], b0 = P32[m][o][0];
      u32 a1 = P32[m][e][1], b1 = P32[m][o][1];
      asm("v_permlane32_swap_b32 %0, %1" : "+v"(a0), "+v"(b0));
      asm("v_permlane32_swap_b32 %0, %1" : "+v"(a1), "+v"(b1));
      f.u[0] = a0; f.u[1] = a1; f.u[2] = b0; f.u[3] = b1;
#endif
      pf[kt] = f.s;
    }

    __builtin_amdgcn_s_setprio(1);
#pragma unroll
    for (int kt = 0; kt < 4; ++kt) {
      lacc = MFMA32(pf[kt], onesf, lacc);
#pragma unroll
      for (int nt = 0; nt < 4; ++nt) {
        v8s vf = *(const v8s*)&smem[16384 + vo + (nt*32 + l32)*64 + vfo[kt]];
        oacc[nt] = MFMA32(pf[kt], vf, oacc[nt]);
      }
    }
    __builtin_amdgcn_s_setprio(0);
  }

  const int b = bh >> 3, hd = bh & 7;
#pragma unroll
  for (int reg = 0; reg < 16; ++reg) {
    int q = q0 + wv*32 + (reg&3) + 8*(reg>>2) + 4*h;
    float inv = 1.0f / lacc[reg];
    size_t base = ((size_t)(b*2048 + q))*1024 + hd*128;
#pragma unroll
    for (int nt = 0; nt < 4; ++nt)
      O[base + nt*32 + l32] = f2b(oacc[nt][reg] * inv);
  }
}

// ---------------------------------------------------------------------------
// Kernel 3: output projection — R21 split-K x4 (R10-measured, unchanged).
// ---------------------------------------------------------------------------
__global__ __launch_bounds__(256) void outproj(
    const u16* __restrict__ A, const float* __restrict__ Ww,
    float* __restrict__ P)    // partials [4][8192][128] f32
{
  __shared__ u16 As[2][2048];  // [buf][2 kt][32 m][32 k]
  __shared__ u16 Ws[2][8192];  // [buf][2 kt][128 n][32 k]

  const int tid = threadIdx.x, wv = tid>>6, lane = tid&63;
  const int quad = lane>>4, l16 = lane&15;
  const int r4 = lane>>2, c4 = lane&3;
  const int m0 = (blockIdx.x >> 2) * 32;
  const int k0 = (blockIdx.x & 3) * 256;

  v4f acc[2][2];   // [mi][nj], nt = wv*2 + nj
#pragma unroll
  for (int i=0;i<2;i++)
#pragma unroll
    for (int j=0;j<2;j++) acc[i][j] = (v4f){0.f,0.f,0.f,0.f};

  auto stage = [&](int kb, int buf) {
    {  // A tile: 4 regions, one per wave (bf16 internal -> gl16)
      int kt = wv >> 1, rg = wv & 1;
      int row = rg*16 + r4;
      gl16(A + (size_t)(m0+row)*1024 + k0 + kb + kt*32 + c4*8, &As[buf][kt*1024 + rg*512 + lane*8]);
    }
    for (int idx = wv; idx < 16; idx += 4) {   // W tile: fp32 -> bf16 staging
      int kt = idx >> 3, rg = idx & 7;
      int row = rg*16 + r4;
      stage8f(Ww + (size_t)row*1024 + k0 + kb + kt*32 + c4*8, &Ws[buf][kt*4096 + rg*512 + lane*8]);
    }
  };

  stage(0, 0);
  for (int kb = 0; kb < 256; kb += 64) {
    const int cur = (kb >> 6) & 1;
    __syncthreads();   // drains stage(kb) + all waves done reading buf cur^1
    if (kb + 64 < 256) stage(kb + 64, cur ^ 1);
#pragma unroll
    for (int ks = 0; ks < 2; ++ks) {
      v8s af0 = *(const v8s*)&As[cur][ks*1024 + (l16)*32 + quad*8];
      v8s af1 = *(const v8s*)&As[cur][ks*1024 + (16 + l16)*32 + quad*8];
#pragma unroll
      for (int nj = 0; nj < 2; ++nj) {
        v8s bf = *(const v8s*)&Ws[cur][ks*4096 + ((wv*2+nj)*16 + l16)*32 + quad*8];
        acc[0][nj] = MFMA16(af0, bf, acc[0][nj]);
        acc[1][nj] = MFMA16(af1, bf, acc[1][nj]);
      }
    }
  }

  float* out = P + (size_t)(blockIdx.x & 3) * 1048576;   // partial kz plane
#pragma unroll
  for (int nj = 0; nj < 2; ++nj) {
    int col = (wv*2+nj)*16 + l16;
#pragma unroll
    for (int mi = 0; mi < 2; ++mi) {
#pragma unroll
      for (int r = 0; r < 4; ++r) {
        int row = m0 + mi*16 + quad*4 + r;
        out[(size_t)row*128 + col] = acc[mi][nj][r];
      }
    }
  }
}

// reduce: out = P0+P1+P2+P3 + bias.  1024 blocks x 256 thr x 4 f32 = 1,048,576.
__global__ __launch_bounds__(256) void outred(
    const float* __restrict__ P, const float* __restrict__ Wb,
    float* __restrict__ out)
{
  int i0 = (blockIdx.x*256 + threadIdx.x)*4;
  float4 a = *(const float4*)&P[i0];
  float4 b = *(const float4*)&P[1048576 + i0];
  float4 c = *(const float4*)&P[2097152 + i0];
  float4 d = *(const float4*)&P[3145728 + i0];
  float4 bv = *(const float4*)&Wb[i0 & 127];
  float4 r;
  r.x = a.x + b.x + c.x + d.x + bv.x;
  r.y = a.y + b.y + c.y + d.y + bv.y;
  r.z = a.z + b.z + c.z + d.z + bv.z;
  r.w = a.w + b.w + c.w + d.w + bv.w;
  *(float4*)&out[i0] = r;
}

// ---------------------------------------------------------------------------
extern "C" void kernel_launch(void* const* d_in, const int* in_sizes, int n_in,
                              void* d_out, int out_size, void* d_ws, size_t ws_size,
                              hipStream_t stream) {
  const float* Q   = (const float*)d_in[0];
  const float* K   = (const float*)d_in[1];
  const float* V   = (const float*)d_in[2];
  const float* WQw = (const float*)d_in[3];
  const float* WQb = (const float*)d_in[4];
  const float* WKw = (const float*)d_in[5];
  const float* WKb = (const float*)d_in[6];
  const float* WVw = (const float*)d_in[7];
  const float* WVb = (const float*)d_in[8];
  const float* Ww  = (const float*)d_in[9];
  const float* Wb  = (const float*)d_in[10];
  u16* ws = (u16*)d_ws;

  const size_t SZ = (size_t)4*8*2048*128;    // 8,388,608 elems per tensor
  u16* Qp = ws;
  u16* Kp = Qp + SZ;
  u16* Vt = Kp + SZ;
  u16* Ow = Vt + SZ;
  float* Pp = (float*)ws;   // partials overlay Qp+Kp (dead after attn): 16.8MB < 32MB

  // cvt outputs overlay the Ow region (7.1MB < 16.8MB); dead before attn
  // writes Ow (proj consumes them, then attn runs).
  u16* Xq = Ow;
  u16* Xk = Xq + 1048576;
  u16* Xv = Xk + 1048576;
  u16* Wq = Xv + 1048576;
  u16* Wk = Wq + 131072;
  u16* Wv = Wk + 131072;

  hipLaunchKernelGGL(cvt, dim3(512,6), dim3(256), 0, stream,
                     Q,K,V,WQw,WKw,WVw, Xq,Xk,Xv,Wq,Wk,Wv);
  hipLaunchKernelGGL(proj_qkv, dim3(64,8,3), dim3(256), 0, stream,
                     Xq,Xk,Xv,Wq,Wk,Wv, WQb,WKb,WVb, Qp,Kp,Vt);
  hipLaunchKernelGGL(attn, dim3(512), dim3(256), 0, stream, Qp,Kp,Vt,Ow);
  hipLaunchKernelGGL(outproj, dim3(1024), dim3(256), 0, stream, Ow, Ww, Pp);
  hipLaunchKernelGGL(outred, dim3(1024), dim3(256), 0, stream, Pp, Wb, (float*)d_out);
}